// Round 10
// baseline (4129.411 us; speedup 1.0000x reference)
//
#include <hip/hip_runtime.h>
#include <hip/hip_bf16.h>

#define TB 64
#define TT 12
#define TK 4
#define TN 400
#define TD 64
#define TE 16
#define QP 1664      // padded sxr rows: 1600 -> 26*64
#define MP 416       // padded supports K: 400 -> 13*32

typedef unsigned short ushort_t;
typedef __attribute__((ext_vector_type(8))) short short8v;
typedef __attribute__((ext_vector_type(4))) float float4v;
typedef __attribute__((ext_vector_type(4))) unsigned short us4;
typedef __attribute__((ext_vector_type(8))) unsigned short us8;

__device__ __forceinline__ float bf2f(ushort_t u) {
    union { unsigned int i; float f; } v; v.i = ((unsigned int)u) << 16; return v.f;
}
__device__ __forceinline__ ushort_t f2bf(float f) {
    union { float f; unsigned int i; } v; v.f = f;
    unsigned int u = v.i;
    return (ushort_t)((u + 0x7fffu + ((u >> 16) & 1u)) >> 16);
}

// ---------------------------------------------------------------- embt (LN of node+time embeddings)
__global__ void k_embt(const float* __restrict__ node, const float* __restrict__ timee,
                       const float* __restrict__ g, const float* __restrict__ b,
                       float* __restrict__ embt) {
    int id = blockIdx.x * blockDim.x + threadIdx.x;
    if (id >= TT * TN) return;
    int t = id / TN, n = id % TN;
    float v[TE];
    float s = 0.f;
#pragma unroll
    for (int e = 0; e < TE; e++) { v[e] = node[n * TE + e] + timee[t * TE + e]; s += v[e]; }
    float mean = s * (1.f / TE);
    float s2 = 0.f;
#pragma unroll
    for (int e = 0; e < TE; e++) { float d = v[e] - mean; s2 += d * d; }
    float rstd = rsqrtf(s2 * (1.f / TE) + 1e-12f);
#pragma unroll
    for (int e = 0; e < TE; e++) embt[(size_t)id * TE + e] = (v[e] - mean) * rstd * g[e] + b[e];
}

// ---------------------------------------------------------------- supports row-softmax -> supN bf16 [t][n][MP] (+diag fp32)
__global__ __launch_bounds__(128) void k_supports(const float* __restrict__ embt,
                                                  ushort_t* __restrict__ supN,
                                                  float* __restrict__ diag) {
    int t = blockIdx.x / TN, n = blockIdx.x % TN;
    int tid = threadIdx.x;
    __shared__ float row[TE];
    __shared__ float red[128];
    if (tid < TE) row[tid] = embt[((size_t)t * TN + n) * TE + tid];
    __syncthreads();
    float l[4];
    float lmax = -1e30f;
#pragma unroll
    for (int it = 0; it < 4; it++) {
        int m = tid + it * 128;
        float d = -1e30f;
        if (m < TN) {
            d = 0.f;
            const float* er = &embt[((size_t)t * TN + m) * TE];
#pragma unroll
            for (int e = 0; e < TE; e++) d += row[e] * er[e];
        }
        l[it] = d;
        lmax = fmaxf(lmax, d);
    }
    red[tid] = lmax; __syncthreads();
    for (int s = 64; s > 0; s >>= 1) { if (tid < s) red[tid] = fmaxf(red[tid], red[tid + s]); __syncthreads(); }
    float mx = red[0]; __syncthreads();
    float lsum = 0.f;
#pragma unroll
    for (int it = 0; it < 4; it++) {
        int m = tid + it * 128;
        if (m < TN) { l[it] = expf(l[it] - mx); lsum += l[it]; }
    }
    red[tid] = lsum; __syncthreads();
    for (int s = 64; s > 0; s >>= 1) { if (tid < s) red[tid] += red[tid + s]; __syncthreads(); }
    float inv = 1.f / red[0];
    ushort_t* srow = supN + ((size_t)t * TN + n) * MP;
#pragma unroll
    for (int it = 0; it < 4; it++) {
        int m = tid + it * 128;
        if (m < TN) {
            float v = l[it] * inv;
            srow[m] = f2bf(v);
            if (m == n) diag[t * TN + n] = v;
        }
    }
    if (tid < MP - TN) srow[TN + tid] = 0;  // zero K-pad
}

// ---------------------------------------------------------------- fp32 M[n][idx] (R2-proven): idx = cheb*4096 + d_in*64 + o
__global__ __launch_bounds__(256) void k_mix(const float* __restrict__ emb, const float* __restrict__ wp,
                                             const float* __restrict__ bp, float* __restrict__ M,
                                             float* __restrict__ bias) {
    int n = blockIdx.x;
    __shared__ float ev[TE];
    if (threadIdx.x < TE) ev[threadIdx.x] = emb[n * TE + threadIdx.x];
    __syncthreads();
    for (int idx = threadIdx.x; idx < 128 * TD; idx += 256) {
        float s = 0.f;
#pragma unroll
        for (int e = 0; e < TE; e++) s += ev[e] * wp[(size_t)e * 8192 + idx];
        M[(size_t)n * 8192 + idx] = s;
    }
    if (threadIdx.x < TD) {
        float s = 0.f;
#pragma unroll
        for (int e = 0; e < TE; e++) s += ev[e] * bp[e * TD + threadIdx.x];
        bias[n * TD + threadIdx.x] = s;
    }
}

// ---------------------------------------------------------------- Xg[bc][q] bf16 transpose of sxr (zero-padded q>=1600)
__global__ __launch_bounds__(256) void k_prepX(const float* __restrict__ sx, ushort_t* __restrict__ Xg,
                                               int t0, size_t tstride) {
    const int qt = blockIdx.x;          // 0..25
    const int bct = blockIdx.y;         // 0..15
    const int t = t0 + blockIdx.z;
    ushort_t* Xgt = Xg + (size_t)blockIdx.z * tstride;
    const int tid = threadIdx.x;
    __shared__ ushort_t Ls[64][264];
    for (int idx = tid; idx < 4096; idx += 256) {
        int qr = idx >> 6, u = idx & 63;
        int q = qt * 64 + qr;
        us4 z;
        if (q < 1600) {
            int bc = bct * 256 + u * 4;
            int b = bc >> 6, c = bc & 63;
            const float4 v = *(const float4*)&sx[((((size_t)b * TT + t) * TK + (q & 3)) * TN + (q >> 2)) * TD + c];
            z[0] = f2bf(v.x); z[1] = f2bf(v.y); z[2] = f2bf(v.z); z[3] = f2bf(v.w);
        } else { z[0] = 0; z[1] = 0; z[2] = 0; z[3] = 0; }
        *(us4*)&Ls[qr][u * 4] = z;
    }
    __syncthreads();
    const int g = tid >> 3, seg = tid & 7;
    for (int p = 0; p < 8; ++p) {
        int bcl = p * 32 + g;
        us8 wv;
#pragma unroll
        for (int s = 0; s < 8; ++s) wv[s] = Ls[seg * 8 + s][bcl];
        *(us8*)&Xgt[(size_t)(bct * 256 + bcl) * QP + qt * 64 + seg * 8] = wv;
    }
}

// ---------------------------------------------------------------- xg1[p][bc] bf16 = supports @ X + rank-term (MFMA)
__global__ __launch_bounds__(256) void k_xg1(const ushort_t* __restrict__ Xg, const ushort_t* __restrict__ supN,
                                             const float* __restrict__ diag, const float* __restrict__ rv,
                                             ushort_t* __restrict__ xg1, int t0, size_t xgstride, size_t x1stride) {
    const int ntile = blockIdx.x;       // 0..4 (80 rows each)
    const int bct = blockIdx.y;         // 0..15 (256 cols each)
    const int zi = blockIdx.z;
    const int i = zi & 3, tz = zi >> 2;
    const int t = t0 + tz;
    const ushort_t* Xgt = Xg + (size_t)tz * xgstride;
    ushort_t* x1t = xg1 + (size_t)tz * x1stride;
    const int tid = threadIdx.x;
    const int w = tid >> 6, l = tid & 63;
    const int lr = l & 15, lk = (l >> 4) * 8;
    const int n0 = ntile * 80, bc0 = bct * 256;
    __shared__ ushort_t As[80][40];
    __shared__ ushort_t Xs[256][40];
    float4v acc[5][4] = {};
    const ushort_t* supt = supN + (size_t)t * TN * MP;
    for (int mc = 0; mc < 13; ++mc) {
        const int m0 = mc * 32;
        for (int idx = tid; idx < 640; idx += 256) {
            int r = idx >> 3, s = idx & 7;
            *(us4*)&As[r][s * 4] = *(const us4*)&supt[(size_t)(n0 + r) * MP + m0 + s * 4];
        }
        for (int idx = tid; idx < 1024; idx += 256) {
            int r = idx >> 2, s = idx & 3;
            *(us8*)&Xs[r][s * 8] = *(const us8*)&Xgt[(size_t)(bc0 + r) * QP + i * 400 + m0 + s * 8];
        }
        __syncthreads();
        short8v a[5], bfr[4];
#pragma unroll
        for (int fr = 0; fr < 5; ++fr) a[fr] = *(const short8v*)&As[fr * 16 + lr][lk];
#pragma unroll
        for (int ct = 0; ct < 4; ++ct) bfr[ct] = *(const short8v*)&Xs[w * 64 + ct * 16 + lr][lk];
#pragma unroll
        for (int fr = 0; fr < 5; ++fr)
#pragma unroll
            for (int ct = 0; ct < 4; ++ct)
                acc[fr][ct] = __builtin_amdgcn_mfma_f32_16x16x32_bf16(a[fr], bfr[ct], acc[fr][ct], 0, 0, 0);
        __syncthreads();
    }
    const float4 rv4 = *(const float4*)&rv[t * TK];
    const float rvj[4] = {rv4.x, rv4.y, rv4.z, rv4.w};
#pragma unroll
    for (int fr = 0; fr < 5; ++fr) {
        const int nb = n0 + fr * 16 + ((l >> 4) << 2);
        const float4 dg4 = *(const float4*)&diag[t * TN + nb];
        const float dg[4] = {dg4.x, dg4.y, dg4.z, dg4.w};
#pragma unroll
        for (int ct = 0; ct < 4; ++ct) {
            const int bc = bc0 + w * 64 + ct * 16 + lr;
            float rs[4] = {0.f, 0.f, 0.f, 0.f};
            for (int j = i; j < 4; ++j) {
                us4 xv = *(const us4*)&Xgt[(size_t)bc * QP + j * 400 + nb];
#pragma unroll
                for (int r = 0; r < 4; ++r) rs[r] += rvj[j] * bf2f(xv[r]);
            }
#pragma unroll
            for (int r = 0; r < 4; ++r) {
                float val = acc[fr][ct][r] + dg[r] * rs[r];
                x1t[(size_t)(i * TN + nb + r) * 4096 + bc] = f2bf(val);
            }
        }
    }
}

// ---------------------------------------------------------------- head v10: R5-proven fp32 math, i-dim split in two halves
// to halve LDS (34.8KB -> 4 blocks/CU). Numerics identical to R5.
__global__ __launch_bounds__(256, 4) void k_head10(const float* __restrict__ sx, const ushort_t* __restrict__ xg1,
                                                   const float* __restrict__ Mn, const float* __restrict__ Mt,
                                                   const float* __restrict__ bn, const float* __restrict__ bt,
                                                   const int* __restrict__ idxs,
                                                   const float* __restrict__ gg, const float* __restrict__ gb,
                                                   const float* __restrict__ og, const float* __restrict__ ob,
                                                   float* __restrict__ out, int t0, size_t x1stride) {
    const int n = blockIdx.x;
    const int tz = blockIdx.y;
    const int t = t0 + tz;
    const ushort_t* x1t = xg1 + (size_t)tz * x1stride;
    const int tid = threadIdx.x;
    const int tx = tid & 15, ty = tid >> 4;
    const int o0 = tx * 4, b0 = ty * 4;
    __shared__ __align__(16) float Ml[64][68];
    __shared__ __align__(16) float Zl[64][68];
    float accout[4][4] = {};
    float g4[4], gb4[4];
#pragma unroll
    for (int c = 0; c < 4; c++) { g4[c] = gg[o0 + c]; gb4[c] = gb[o0 + c]; }
    const float* mnp = Mn + (size_t)n * 8192;

    for (int k = 0; k < TK; k++) {
        int tau = idxs[t * TK + k];
        const float* mtp = Mt + (size_t)tau * 8192;
        float acch[4][4] = {};
#pragma unroll
        for (int ih = 0; ih < 2; ih++) {
            // stage Ml half: i = ih*64 + il
            for (int idx = tid; idx < 1024; idx += 256) {
                int il = idx >> 4, o4 = idx & 15;
                const float4 a = *(const float4*)&mnp[(ih * 64 + il) * 64 + o4 * 4];
                const float4 c = *(const float4*)&mtp[(ih * 64 + il) * 64 + o4 * 4];
                float4 r; r.x = a.x + c.x; r.y = a.y + c.y; r.z = a.z + c.z; r.w = a.w + c.w;
                *(float4*)&Ml[il][o4 * 4] = r;
            }
            // stage Zl half
            if (ih == 0) {
                for (int idx = tid; idx < 1024; idx += 256) {
                    int b = idx >> 4, c4 = idx & 15;
                    const float4 v = *(const float4*)&sx[((((size_t)b * TT + t) * TK + k) * TN + n) * TD + c4 * 4];
                    *(float4*)&Zl[b][c4 * 4] = v;
                }
            } else {
                for (int idx = tid; idx < 512; idx += 256) {
                    int b = idx >> 3, s = idx & 7;
                    us8 xv = *(const us8*)&x1t[((size_t)n * TK + k) * 4096 + b * 64 + s * 8];
                    float* zp = &Zl[b][s * 8];
#pragma unroll
                    for (int q = 0; q < 8; q++) zp[q] = bf2f(xv[q]);
                }
            }
            __syncthreads();
            for (int i0 = 0; i0 < 64; i0 += 4) {
                float m[4][4];
#pragma unroll
                for (int q = 0; q < 4; q++) {
                    float4 mv = *(const float4*)&Ml[i0 + q][o0];
                    m[q][0] = mv.x; m[q][1] = mv.y; m[q][2] = mv.z; m[q][3] = mv.w;
                }
#pragma unroll
                for (int r = 0; r < 4; r++) {
                    float4 zv = *(const float4*)&Zl[b0 + r][i0];
                    float z[4] = {zv.x, zv.y, zv.z, zv.w};
#pragma unroll
                    for (int q = 0; q < 4; q++)
#pragma unroll
                        for (int c = 0; c < 4; c++) acch[r][c] += z[q] * m[q][c];
                }
            }
            __syncthreads();
        }
#pragma unroll
        for (int c = 0; c < 4; c++) {
            float bias = bn[n * TD + o0 + c] + bt[tau * TD + o0 + c];
#pragma unroll
            for (int r = 0; r < 4; r++) acch[r][c] += bias;
        }
#pragma unroll
        for (int r = 0; r < 4; r++) {
            float s1 = acch[r][0] + acch[r][1] + acch[r][2] + acch[r][3];
            float s2 = acch[r][0] * acch[r][0] + acch[r][1] * acch[r][1] +
                       acch[r][2] * acch[r][2] + acch[r][3] * acch[r][3];
#pragma unroll
            for (int mk = 1; mk < 16; mk <<= 1) { s1 += __shfl_xor(s1, mk); s2 += __shfl_xor(s2, mk); }
            float mean = s1 * (1.f / TD);
            float var  = s2 * (1.f / TD) - mean * mean;
            float rstd = rsqrtf(var + 1e-5f);
#pragma unroll
            for (int c = 0; c < 4; c++) accout[r][c] += (acch[r][c] - mean) * rstd * g4[c] + gb4[c];
        }
    }

    // ---- R5-verbatim epilogue ----
    float og4[4], ob4[4];
#pragma unroll
    for (int c = 0; c < 4; c++) { og4[c] = og[o0 + c]; ob4[c] = ob[o0 + c]; }
#pragma unroll
    for (int r = 0; r < 4; r++) {
        float pre[4];
#pragma unroll
        for (int c = 0; c < 4; c++) pre[c] = accout[r][c] * 0.25f;
        float s1 = pre[0] + pre[1] + pre[2] + pre[3];
        float s2 = pre[0] * pre[0] + pre[1] * pre[1] + pre[2] * pre[2] + pre[3] * pre[3];
#pragma unroll
        for (int mk2 = 1; mk2 < 16; mk2 <<= 1) { s1 += __shfl_xor(s1, mk2); s2 += __shfl_xor(s2, mk2); }
        float mean = s1 * (1.f / TD);
        float var  = s2 * (1.f / TD) - mean * mean;
        float rstd = rsqrtf(var + 1e-5f);
        float mk[4] = {0, 0, 0, 0};
        const float* sxp = &sx[(((size_t)(b0 + r) * TT + t) * TK) * TN * TD + (size_t)n * TD + o0];
#pragma unroll
        for (int k = 0; k < TK; k++) {
            float4 sv = *(const float4*)&sxp[(size_t)k * TN * TD];
            mk[0] += sv.x; mk[1] += sv.y; mk[2] += sv.z; mk[3] += sv.w;
        }
        float4 res;
        res.x = (pre[0] - mean) * rstd * og4[0] + ob4[0] + 0.25f * mk[0];
        res.y = (pre[1] - mean) * rstd * og4[1] + ob4[1] + 0.25f * mk[1];
        res.z = (pre[2] - mean) * rstd * og4[2] + ob4[2] + 0.25f * mk[2];
        res.w = (pre[3] - mean) * rstd * og4[3] + ob4[3] + 0.25f * mk[3];
        *reinterpret_cast<float4*>(&out[(((size_t)(b0 + r) * TT + t) * TN + n) * TD + o0]) = res;
    }
}

extern "C" void kernel_launch(void* const* d_in, const int* in_sizes, int n_in,
                              void* d_out, int out_size, void* d_ws, size_t ws_size,
                              hipStream_t stream) {
    (void)in_sizes; (void)n_in; (void)out_size;
    const float* sx    = (const float*)d_in[1];
    const float* rv    = (const float*)d_in[2];
    const int*   idxs  = (const int*)d_in[3];
    const float* node  = (const float*)d_in[4];
    const float* timee = (const float*)d_in[5];
    const float* leg   = (const float*)d_in[6];
    const float* leb   = (const float*)d_in[7];
    const float* wp    = (const float*)d_in[8];
    const float* bp    = (const float*)d_in[9];
    const float* gg    = (const float*)d_in[10];
    const float* gb    = (const float*)d_in[11];
    const float* og    = (const float*)d_in[12];
    const float* ob    = (const float*)d_in[13];
    float* out = (float*)d_out;

    char* w = (char*)d_ws;
    size_t off = 0;
    auto alloc = [&](size_t bytes) { size_t o = off; off = (off + bytes + 255) & ~(size_t)255; return o; };
    float*    embt = (float*)(w + alloc((size_t)TT * TN * TE * 4));
    ushort_t* supN = (ushort_t*)(w + alloc((size_t)TT * TN * MP * 2));
    float*    diag = (float*)(w + alloc((size_t)TT * TN * 4));
    float*    Mn   = (float*)(w + alloc((size_t)TN * 8192 * 4));
    float*    Mt   = (float*)(w + alloc((size_t)TT * 8192 * 4));
    float*    bn   = (float*)(w + alloc((size_t)TN * TD * 4));
    float*    bt   = (float*)(w + alloc((size_t)TT * TD * 4));
    const size_t xg_elems = (size_t)4096 * QP;     // per-t Xg (ushort)
    const size_t x1_elems = (size_t)1600 * 4096;   // per-t xg1 (ushort)
    const size_t small_end = off;
    const bool full = ws_size >= small_end + 12 * (xg_elems + x1_elems) * 2 + 1024;
    const int nt = full ? TT : 1;
    ushort_t* Xg = (ushort_t*)(w + alloc((size_t)nt * xg_elems * 2));
    ushort_t* x1 = (ushort_t*)(w + alloc((size_t)nt * x1_elems * 2));

    k_embt<<<dim3((TT * TN + 255) / 256), 256, 0, stream>>>(node, timee, leg, leb, embt);
    k_supports<<<dim3(TT * TN), 128, 0, stream>>>(embt, supN, diag);
    k_mix<<<dim3(TN), 256, 0, stream>>>(node, wp, bp, Mn, bn);
    k_mix<<<dim3(TT), 256, 0, stream>>>(timee, wp, bp, Mt, bt);
    if (full) {
        k_prepX<<<dim3(26, 16, TT), 256, 0, stream>>>(sx, Xg, 0, xg_elems);
        k_xg1<<<dim3(5, 16, 4 * TT), 256, 0, stream>>>(Xg, supN, diag, rv, x1, 0, xg_elems, x1_elems);
        k_head10<<<dim3(TN, TT), 256, 0, stream>>>(sx, x1, Mn, Mt, bn, bt, idxs, gg, gb, og, ob, out, 0, x1_elems);
    } else {
        for (int t = 0; t < TT; ++t) {
            k_prepX<<<dim3(26, 16, 1), 256, 0, stream>>>(sx, Xg, t, 0);
            k_xg1<<<dim3(5, 16, 4), 256, 0, stream>>>(Xg, supN, diag, rv, x1, t, 0, 0);
            k_head10<<<dim3(TN, 1), 256, 0, stream>>>(sx, x1, Mn, Mt, bn, bt, idxs, gg, gb, og, ob, out, t, 0);
        }
    }
}

// Round 11
// 1767.593 us; speedup vs baseline: 2.3362x; 2.3362x over previous
//
#include <hip/hip_runtime.h>
#include <hip/hip_bf16.h>

#define TB 64
#define TT 12
#define TK 4
#define TN 400
#define TD 64
#define TE 16
#define QP 1664      // padded sxr rows: 1600 -> 26*64
#define MP 416       // padded supports K: 400 -> 13*32

typedef unsigned short ushort_t;
typedef __attribute__((ext_vector_type(8))) short short8v;
typedef __attribute__((ext_vector_type(4))) float float4v;
typedef __attribute__((ext_vector_type(4))) unsigned short us4;
typedef __attribute__((ext_vector_type(8))) unsigned short us8;

__device__ __forceinline__ float bf2f(ushort_t u) {
    union { unsigned int i; float f; } v; v.i = ((unsigned int)u) << 16; return v.f;
}
__device__ __forceinline__ ushort_t f2bf(float f) {
    union { float f; unsigned int i; } v; v.f = f;
    unsigned int u = v.i;
    return (ushort_t)((u + 0x7fffu + ((u >> 16) & 1u)) >> 16);
}

// ---------------------------------------------------------------- embt (LN of node+time embeddings)
__global__ void k_embt(const float* __restrict__ node, const float* __restrict__ timee,
                       const float* __restrict__ g, const float* __restrict__ b,
                       float* __restrict__ embt) {
    int id = blockIdx.x * blockDim.x + threadIdx.x;
    if (id >= TT * TN) return;
    int t = id / TN, n = id % TN;
    float v[TE];
    float s = 0.f;
#pragma unroll
    for (int e = 0; e < TE; e++) { v[e] = node[n * TE + e] + timee[t * TE + e]; s += v[e]; }
    float mean = s * (1.f / TE);
    float s2 = 0.f;
#pragma unroll
    for (int e = 0; e < TE; e++) { float d = v[e] - mean; s2 += d * d; }
    float rstd = rsqrtf(s2 * (1.f / TE) + 1e-12f);
#pragma unroll
    for (int e = 0; e < TE; e++) embt[(size_t)id * TE + e] = (v[e] - mean) * rstd * g[e] + b[e];
}

// ---------------------------------------------------------------- supports row-softmax -> supN bf16 [t][n][MP] (+diag fp32)
__global__ __launch_bounds__(128) void k_supports(const float* __restrict__ embt,
                                                  ushort_t* __restrict__ supN,
                                                  float* __restrict__ diag) {
    int t = blockIdx.x / TN, n = blockIdx.x % TN;
    int tid = threadIdx.x;
    __shared__ float row[TE];
    __shared__ float red[128];
    if (tid < TE) row[tid] = embt[((size_t)t * TN + n) * TE + tid];
    __syncthreads();
    float l[4];
    float lmax = -1e30f;
#pragma unroll
    for (int it = 0; it < 4; it++) {
        int m = tid + it * 128;
        float d = -1e30f;
        if (m < TN) {
            d = 0.f;
            const float* er = &embt[((size_t)t * TN + m) * TE];
#pragma unroll
            for (int e = 0; e < TE; e++) d += row[e] * er[e];
        }
        l[it] = d;
        lmax = fmaxf(lmax, d);
    }
    red[tid] = lmax; __syncthreads();
    for (int s = 64; s > 0; s >>= 1) { if (tid < s) red[tid] = fmaxf(red[tid], red[tid + s]); __syncthreads(); }
    float mx = red[0]; __syncthreads();
    float lsum = 0.f;
#pragma unroll
    for (int it = 0; it < 4; it++) {
        int m = tid + it * 128;
        if (m < TN) { l[it] = expf(l[it] - mx); lsum += l[it]; }
    }
    red[tid] = lsum; __syncthreads();
    for (int s = 64; s > 0; s >>= 1) { if (tid < s) red[tid] += red[tid + s]; __syncthreads(); }
    float inv = 1.f / red[0];
    ushort_t* srow = supN + ((size_t)t * TN + n) * MP;
#pragma unroll
    for (int it = 0; it < 4; it++) {
        int m = tid + it * 128;
        if (m < TN) {
            float v = l[it] * inv;
            srow[m] = f2bf(v);
            if (m == n) diag[t * TN + n] = v;
        }
    }
    if (tid < MP - TN) srow[TN + tid] = 0;  // zero K-pad
}

// ---------------------------------------------------------------- fp32 M[n][idx] (R2-proven): idx = cheb*4096 + d_in*64 + o
__global__ __launch_bounds__(256) void k_mix(const float* __restrict__ emb, const float* __restrict__ wp,
                                             const float* __restrict__ bp, float* __restrict__ M,
                                             float* __restrict__ bias) {
    int n = blockIdx.x;
    __shared__ float ev[TE];
    if (threadIdx.x < TE) ev[threadIdx.x] = emb[n * TE + threadIdx.x];
    __syncthreads();
    for (int idx = threadIdx.x; idx < 128 * TD; idx += 256) {
        float s = 0.f;
#pragma unroll
        for (int e = 0; e < TE; e++) s += ev[e] * wp[(size_t)e * 8192 + idx];
        M[(size_t)n * 8192 + idx] = s;
    }
    if (threadIdx.x < TD) {
        float s = 0.f;
#pragma unroll
        for (int e = 0; e < TE; e++) s += ev[e] * bp[e * TD + threadIdx.x];
        bias[n * TD + threadIdx.x] = s;
    }
}

// ---------------------------------------------------------------- Xg[bc][q] bf16 transpose of sxr (zero-padded q>=1600)
__global__ __launch_bounds__(256) void k_prepX(const float* __restrict__ sx, ushort_t* __restrict__ Xg,
                                               int t0, size_t tstride) {
    const int qt = blockIdx.x;          // 0..25
    const int bct = blockIdx.y;         // 0..15
    const int t = t0 + blockIdx.z;
    ushort_t* Xgt = Xg + (size_t)blockIdx.z * tstride;
    const int tid = threadIdx.x;
    __shared__ ushort_t Ls[64][264];
    for (int idx = tid; idx < 4096; idx += 256) {
        int qr = idx >> 6, u = idx & 63;
        int q = qt * 64 + qr;
        us4 z;
        if (q < 1600) {
            int bc = bct * 256 + u * 4;
            int b = bc >> 6, c = bc & 63;
            const float4 v = *(const float4*)&sx[((((size_t)b * TT + t) * TK + (q & 3)) * TN + (q >> 2)) * TD + c];
            z[0] = f2bf(v.x); z[1] = f2bf(v.y); z[2] = f2bf(v.z); z[3] = f2bf(v.w);
        } else { z[0] = 0; z[1] = 0; z[2] = 0; z[3] = 0; }
        *(us4*)&Ls[qr][u * 4] = z;
    }
    __syncthreads();
    const int g = tid >> 3, seg = tid & 7;
    for (int p = 0; p < 8; ++p) {
        int bcl = p * 32 + g;
        us8 wv;
#pragma unroll
        for (int s = 0; s < 8; ++s) wv[s] = Ls[seg * 8 + s][bcl];
        *(us8*)&Xgt[(size_t)(bct * 256 + bcl) * QP + qt * 64 + seg * 8] = wv;
    }
}

// ---------------------------------------------------------------- xg1[p][bc] bf16 = supports @ X + rank-term (MFMA)
__global__ __launch_bounds__(256) void k_xg1(const ushort_t* __restrict__ Xg, const ushort_t* __restrict__ supN,
                                             const float* __restrict__ diag, const float* __restrict__ rv,
                                             ushort_t* __restrict__ xg1, int t0, size_t xgstride, size_t x1stride) {
    const int ntile = blockIdx.x;       // 0..4 (80 rows each)
    const int bct = blockIdx.y;         // 0..15 (256 cols each)
    const int zi = blockIdx.z;
    const int i = zi & 3, tz = zi >> 2;
    const int t = t0 + tz;
    const ushort_t* Xgt = Xg + (size_t)tz * xgstride;
    ushort_t* x1t = xg1 + (size_t)tz * x1stride;
    const int tid = threadIdx.x;
    const int w = tid >> 6, l = tid & 63;
    const int lr = l & 15, lk = (l >> 4) * 8;
    const int n0 = ntile * 80, bc0 = bct * 256;
    __shared__ ushort_t As[80][40];
    __shared__ ushort_t Xs[256][40];
    float4v acc[5][4] = {};
    const ushort_t* supt = supN + (size_t)t * TN * MP;
    for (int mc = 0; mc < 13; ++mc) {
        const int m0 = mc * 32;
        for (int idx = tid; idx < 640; idx += 256) {
            int r = idx >> 3, s = idx & 7;
            *(us4*)&As[r][s * 4] = *(const us4*)&supt[(size_t)(n0 + r) * MP + m0 + s * 4];
        }
        for (int idx = tid; idx < 1024; idx += 256) {
            int r = idx >> 2, s = idx & 3;
            *(us8*)&Xs[r][s * 8] = *(const us8*)&Xgt[(size_t)(bc0 + r) * QP + i * 400 + m0 + s * 8];
        }
        __syncthreads();
        short8v a[5], bfr[4];
#pragma unroll
        for (int fr = 0; fr < 5; ++fr) a[fr] = *(const short8v*)&As[fr * 16 + lr][lk];
#pragma unroll
        for (int ct = 0; ct < 4; ++ct) bfr[ct] = *(const short8v*)&Xs[w * 64 + ct * 16 + lr][lk];
#pragma unroll
        for (int fr = 0; fr < 5; ++fr)
#pragma unroll
            for (int ct = 0; ct < 4; ++ct)
                acc[fr][ct] = __builtin_amdgcn_mfma_f32_16x16x32_bf16(a[fr], bfr[ct], acc[fr][ct], 0, 0, 0);
        __syncthreads();
    }
    const float4 rv4 = *(const float4*)&rv[t * TK];
    const float rvj[4] = {rv4.x, rv4.y, rv4.z, rv4.w};
#pragma unroll
    for (int fr = 0; fr < 5; ++fr) {
        const int nb = n0 + fr * 16 + ((l >> 4) << 2);
        const float4 dg4 = *(const float4*)&diag[t * TN + nb];
        const float dg[4] = {dg4.x, dg4.y, dg4.z, dg4.w};
#pragma unroll
        for (int ct = 0; ct < 4; ++ct) {
            const int bc = bc0 + w * 64 + ct * 16 + lr;
            float rs[4] = {0.f, 0.f, 0.f, 0.f};
            for (int j = i; j < 4; ++j) {
                us4 xv = *(const us4*)&Xgt[(size_t)bc * QP + j * 400 + nb];
#pragma unroll
                for (int r = 0; r < 4; ++r) rs[r] += rvj[j] * bf2f(xv[r]);
            }
#pragma unroll
            for (int r = 0; r < 4; ++r) {
                float val = acc[fr][ct][r] + dg[r] * rs[r];
                x1t[(size_t)(i * TN + nb + r) * 4096 + bc] = f2bf(val);
            }
        }
    }
}

// ---------------------------------------------------------------- head v11: R5-proven fp32 math, halved LDS (34.8KB ->
// 4 blocks/CU, LDS-limited), NO register clamp (R10's spill lesson). Numerics identical to R5.
__global__ __launch_bounds__(256) void k_head10(const float* __restrict__ sx, const ushort_t* __restrict__ xg1,
                                                const float* __restrict__ Mn, const float* __restrict__ Mt,
                                                const float* __restrict__ bn, const float* __restrict__ bt,
                                                const int* __restrict__ idxs,
                                                const float* __restrict__ gg, const float* __restrict__ gb,
                                                const float* __restrict__ og, const float* __restrict__ ob,
                                                float* __restrict__ out, int t0, size_t x1stride) {
    const int n = blockIdx.x;
    const int tz = blockIdx.y;
    const int t = t0 + tz;
    const ushort_t* x1t = xg1 + (size_t)tz * x1stride;
    const int tid = threadIdx.x;
    const int tx = tid & 15, ty = tid >> 4;
    const int o0 = tx * 4, b0 = ty * 4;
    __shared__ __align__(16) float Ml[64][68];
    __shared__ __align__(16) float Zl[64][68];
    float accout[4][4] = {};
    float g4[4], gb4[4];
#pragma unroll
    for (int c = 0; c < 4; c++) { g4[c] = gg[o0 + c]; gb4[c] = gb[o0 + c]; }
    const float* mnp = Mn + (size_t)n * 8192;

    for (int k = 0; k < TK; k++) {
        int tau = idxs[t * TK + k];
        const float* mtp = Mt + (size_t)tau * 8192;
        float acch[4][4] = {};
#pragma unroll
        for (int ih = 0; ih < 2; ih++) {
            // stage Ml half: i = ih*64 + il
            for (int idx = tid; idx < 1024; idx += 256) {
                int il = idx >> 4, o4 = idx & 15;
                const float4 a = *(const float4*)&mnp[(ih * 64 + il) * 64 + o4 * 4];
                const float4 c = *(const float4*)&mtp[(ih * 64 + il) * 64 + o4 * 4];
                float4 r; r.x = a.x + c.x; r.y = a.y + c.y; r.z = a.z + c.z; r.w = a.w + c.w;
                *(float4*)&Ml[il][o4 * 4] = r;
            }
            // stage Zl half
            if (ih == 0) {
                for (int idx = tid; idx < 1024; idx += 256) {
                    int b = idx >> 4, c4 = idx & 15;
                    const float4 v = *(const float4*)&sx[((((size_t)b * TT + t) * TK + k) * TN + n) * TD + c4 * 4];
                    *(float4*)&Zl[b][c4 * 4] = v;
                }
            } else {
                for (int idx = tid; idx < 512; idx += 256) {
                    int b = idx >> 3, s = idx & 7;
                    us8 xv = *(const us8*)&x1t[((size_t)n * TK + k) * 4096 + b * 64 + s * 8];
                    float* zp = &Zl[b][s * 8];
#pragma unroll
                    for (int q = 0; q < 8; q++) zp[q] = bf2f(xv[q]);
                }
            }
            __syncthreads();
            for (int i0 = 0; i0 < 64; i0 += 4) {
                float m[4][4];
#pragma unroll
                for (int q = 0; q < 4; q++) {
                    float4 mv = *(const float4*)&Ml[i0 + q][o0];
                    m[q][0] = mv.x; m[q][1] = mv.y; m[q][2] = mv.z; m[q][3] = mv.w;
                }
#pragma unroll
                for (int r = 0; r < 4; r++) {
                    float4 zv = *(const float4*)&Zl[b0 + r][i0];
                    float z[4] = {zv.x, zv.y, zv.z, zv.w};
#pragma unroll
                    for (int q = 0; q < 4; q++)
#pragma unroll
                        for (int c = 0; c < 4; c++) acch[r][c] += z[q] * m[q][c];
                }
            }
            __syncthreads();
        }
#pragma unroll
        for (int c = 0; c < 4; c++) {
            float bias = bn[n * TD + o0 + c] + bt[tau * TD + o0 + c];
#pragma unroll
            for (int r = 0; r < 4; r++) acch[r][c] += bias;
        }
#pragma unroll
        for (int r = 0; r < 4; r++) {
            float s1 = acch[r][0] + acch[r][1] + acch[r][2] + acch[r][3];
            float s2 = acch[r][0] * acch[r][0] + acch[r][1] * acch[r][1] +
                       acch[r][2] * acch[r][2] + acch[r][3] * acch[r][3];
#pragma unroll
            for (int mk = 1; mk < 16; mk <<= 1) { s1 += __shfl_xor(s1, mk); s2 += __shfl_xor(s2, mk); }
            float mean = s1 * (1.f / TD);
            float var  = s2 * (1.f / TD) - mean * mean;
            float rstd = rsqrtf(var + 1e-5f);
#pragma unroll
            for (int c = 0; c < 4; c++) accout[r][c] += (acch[r][c] - mean) * rstd * g4[c] + gb4[c];
        }
    }

    // ---- R5-verbatim epilogue ----
    float og4[4], ob4[4];
#pragma unroll
    for (int c = 0; c < 4; c++) { og4[c] = og[o0 + c]; ob4[c] = ob[o0 + c]; }
#pragma unroll
    for (int r = 0; r < 4; r++) {
        float pre[4];
#pragma unroll
        for (int c = 0; c < 4; c++) pre[c] = accout[r][c] * 0.25f;
        float s1 = pre[0] + pre[1] + pre[2] + pre[3];
        float s2 = pre[0] * pre[0] + pre[1] * pre[1] + pre[2] * pre[2] + pre[3] * pre[3];
#pragma unroll
        for (int mk2 = 1; mk2 < 16; mk2 <<= 1) { s1 += __shfl_xor(s1, mk2); s2 += __shfl_xor(s2, mk2); }
        float mean = s1 * (1.f / TD);
        float var  = s2 * (1.f / TD) - mean * mean;
        float rstd = rsqrtf(var + 1e-5f);
        float mk[4] = {0, 0, 0, 0};
        const float* sxp = &sx[(((size_t)(b0 + r) * TT + t) * TK) * TN * TD + (size_t)n * TD + o0];
#pragma unroll
        for (int k = 0; k < TK; k++) {
            float4 sv = *(const float4*)&sxp[(size_t)k * TN * TD];
            mk[0] += sv.x; mk[1] += sv.y; mk[2] += sv.z; mk[3] += sv.w;
        }
        float4 res;
        res.x = (pre[0] - mean) * rstd * og4[0] + ob4[0] + 0.25f * mk[0];
        res.y = (pre[1] - mean) * rstd * og4[1] + ob4[1] + 0.25f * mk[1];
        res.z = (pre[2] - mean) * rstd * og4[2] + ob4[2] + 0.25f * mk[2];
        res.w = (pre[3] - mean) * rstd * og4[3] + ob4[3] + 0.25f * mk[3];
        *reinterpret_cast<float4*>(&out[(((size_t)(b0 + r) * TT + t) * TN + n) * TD + o0]) = res;
    }
}

extern "C" void kernel_launch(void* const* d_in, const int* in_sizes, int n_in,
                              void* d_out, int out_size, void* d_ws, size_t ws_size,
                              hipStream_t stream) {
    (void)in_sizes; (void)n_in; (void)out_size;
    const float* sx    = (const float*)d_in[1];
    const float* rv    = (const float*)d_in[2];
    const int*   idxs  = (const int*)d_in[3];
    const float* node  = (const float*)d_in[4];
    const float* timee = (const float*)d_in[5];
    const float* leg   = (const float*)d_in[6];
    const float* leb   = (const float*)d_in[7];
    const float* wp    = (const float*)d_in[8];
    const float* bp    = (const float*)d_in[9];
    const float* gg    = (const float*)d_in[10];
    const float* gb    = (const float*)d_in[11];
    const float* og    = (const float*)d_in[12];
    const float* ob    = (const float*)d_in[13];
    float* out = (float*)d_out;

    char* w = (char*)d_ws;
    size_t off = 0;
    auto alloc = [&](size_t bytes) { size_t o = off; off = (off + bytes + 255) & ~(size_t)255; return o; };
    float*    embt = (float*)(w + alloc((size_t)TT * TN * TE * 4));
    ushort_t* supN = (ushort_t*)(w + alloc((size_t)TT * TN * MP * 2));
    float*    diag = (float*)(w + alloc((size_t)TT * TN * 4));
    float*    Mn   = (float*)(w + alloc((size_t)TN * 8192 * 4));
    float*    Mt   = (float*)(w + alloc((size_t)TT * 8192 * 4));
    float*    bn   = (float*)(w + alloc((size_t)TN * TD * 4));
    float*    bt   = (float*)(w + alloc((size_t)TT * TD * 4));
    const size_t xg_elems = (size_t)4096 * QP;     // per-t Xg (ushort)
    const size_t x1_elems = (size_t)1600 * 4096;   // per-t xg1 (ushort)
    const size_t small_end = off;
    const bool full = ws_size >= small_end + 12 * (xg_elems + x1_elems) * 2 + 1024;
    const int nt = full ? TT : 1;
    ushort_t* Xg = (ushort_t*)(w + alloc((size_t)nt * xg_elems * 2));
    ushort_t* x1 = (ushort_t*)(w + alloc((size_t)nt * x1_elems * 2));

    k_embt<<<dim3((TT * TN + 255) / 256), 256, 0, stream>>>(node, timee, leg, leb, embt);
    k_supports<<<dim3(TT * TN), 128, 0, stream>>>(embt, supN, diag);
    k_mix<<<dim3(TN), 256, 0, stream>>>(node, wp, bp, Mn, bn);
    k_mix<<<dim3(TT), 256, 0, stream>>>(timee, wp, bp, Mt, bt);
    if (full) {
        k_prepX<<<dim3(26, 16, TT), 256, 0, stream>>>(sx, Xg, 0, xg_elems);
        k_xg1<<<dim3(5, 16, 4 * TT), 256, 0, stream>>>(Xg, supN, diag, rv, x1, 0, xg_elems, x1_elems);
        k_head10<<<dim3(TN, TT), 256, 0, stream>>>(sx, x1, Mn, Mt, bn, bt, idxs, gg, gb, og, ob, out, 0, x1_elems);
    } else {
        for (int t = 0; t < TT; ++t) {
            k_prepX<<<dim3(26, 16, 1), 256, 0, stream>>>(sx, Xg, t, 0);
            k_xg1<<<dim3(5, 16, 4), 256, 0, stream>>>(Xg, supN, diag, rv, x1, t, 0, 0);
            k_head10<<<dim3(TN, 1), 256, 0, stream>>>(sx, x1, Mn, Mt, bn, bt, idxs, gg, gb, og, ob, out, t, 0);
        }
    }
}

// Round 12
// 952.913 us; speedup vs baseline: 4.3335x; 1.8549x over previous
//
#include <hip/hip_runtime.h>
#include <hip/hip_bf16.h>

#define TB 64
#define TT 12
#define TK 4
#define TN 400
#define TD 64
#define TE 16
#define QP 1664      // padded sxr rows: 1600 -> 26*64
#define MP 416       // padded supports K: 400 -> 13*32

typedef unsigned short ushort_t;
typedef __attribute__((ext_vector_type(8))) short short8v;
typedef __attribute__((ext_vector_type(4))) float float4v;
typedef __attribute__((ext_vector_type(4))) unsigned short us4;
typedef __attribute__((ext_vector_type(8))) unsigned short us8;

__device__ __forceinline__ float bf2f(ushort_t u) {
    union { unsigned int i; float f; } v; v.i = ((unsigned int)u) << 16; return v.f;
}
__device__ __forceinline__ ushort_t f2bf(float f) {
    union { float f; unsigned int i; } v; v.f = f;
    unsigned int u = v.i;
    return (ushort_t)((u + 0x7fffu + ((u >> 16) & 1u)) >> 16);
}

// ---------------------------------------------------------------- embt (LN of node+time embeddings)
__global__ void k_embt(const float* __restrict__ node, const float* __restrict__ timee,
                       const float* __restrict__ g, const float* __restrict__ b,
                       float* __restrict__ embt) {
    int id = blockIdx.x * blockDim.x + threadIdx.x;
    if (id >= TT * TN) return;
    int t = id / TN, n = id % TN;
    float v[TE];
    float s = 0.f;
#pragma unroll
    for (int e = 0; e < TE; e++) { v[e] = node[n * TE + e] + timee[t * TE + e]; s += v[e]; }
    float mean = s * (1.f / TE);
    float s2 = 0.f;
#pragma unroll
    for (int e = 0; e < TE; e++) { float d = v[e] - mean; s2 += d * d; }
    float rstd = rsqrtf(s2 * (1.f / TE) + 1e-12f);
#pragma unroll
    for (int e = 0; e < TE; e++) embt[(size_t)id * TE + e] = (v[e] - mean) * rstd * g[e] + b[e];
}

// ---------------------------------------------------------------- supports row-softmax -> supN bf16 [t][n][MP] (+diag fp32)
__global__ __launch_bounds__(128) void k_supports(const float* __restrict__ embt,
                                                  ushort_t* __restrict__ supN,
                                                  float* __restrict__ diag) {
    int t = blockIdx.x / TN, n = blockIdx.x % TN;
    int tid = threadIdx.x;
    __shared__ float row[TE];
    __shared__ float red[128];
    if (tid < TE) row[tid] = embt[((size_t)t * TN + n) * TE + tid];
    __syncthreads();
    float l[4];
    float lmax = -1e30f;
#pragma unroll
    for (int it = 0; it < 4; it++) {
        int m = tid + it * 128;
        float d = -1e30f;
        if (m < TN) {
            d = 0.f;
            const float* er = &embt[((size_t)t * TN + m) * TE];
#pragma unroll
            for (int e = 0; e < TE; e++) d += row[e] * er[e];
        }
        l[it] = d;
        lmax = fmaxf(lmax, d);
    }
    red[tid] = lmax; __syncthreads();
    for (int s = 64; s > 0; s >>= 1) { if (tid < s) red[tid] = fmaxf(red[tid], red[tid + s]); __syncthreads(); }
    float mx = red[0]; __syncthreads();
    float lsum = 0.f;
#pragma unroll
    for (int it = 0; it < 4; it++) {
        int m = tid + it * 128;
        if (m < TN) { l[it] = expf(l[it] - mx); lsum += l[it]; }
    }
    red[tid] = lsum; __syncthreads();
    for (int s = 64; s > 0; s >>= 1) { if (tid < s) red[tid] += red[tid + s]; __syncthreads(); }
    float inv = 1.f / red[0];
    ushort_t* srow = supN + ((size_t)t * TN + n) * MP;
#pragma unroll
    for (int it = 0; it < 4; it++) {
        int m = tid + it * 128;
        if (m < TN) {
            float v = l[it] * inv;
            srow[m] = f2bf(v);
            if (m == n) diag[t * TN + n] = v;
        }
    }
    if (tid < MP - TN) srow[TN + tid] = 0;  // zero K-pad
}

// ---------------------------------------------------------------- fp32 M[n][idx] (R2-proven): idx = cheb*4096 + d_in*64 + o
__global__ __launch_bounds__(256) void k_mix(const float* __restrict__ emb, const float* __restrict__ wp,
                                             const float* __restrict__ bp, float* __restrict__ M,
                                             float* __restrict__ bias) {
    int n = blockIdx.x;
    __shared__ float ev[TE];
    if (threadIdx.x < TE) ev[threadIdx.x] = emb[n * TE + threadIdx.x];
    __syncthreads();
    for (int idx = threadIdx.x; idx < 128 * TD; idx += 256) {
        float s = 0.f;
#pragma unroll
        for (int e = 0; e < TE; e++) s += ev[e] * wp[(size_t)e * 8192 + idx];
        M[(size_t)n * 8192 + idx] = s;
    }
    if (threadIdx.x < TD) {
        float s = 0.f;
#pragma unroll
        for (int e = 0; e < TE; e++) s += ev[e] * bp[e * TD + threadIdx.x];
        bias[n * TD + threadIdx.x] = s;
    }
}

// ---------------------------------------------------------------- Xg[bc][q] bf16 transpose of sxr (zero-padded q>=1600)
__global__ __launch_bounds__(256) void k_prepX(const float* __restrict__ sx, ushort_t* __restrict__ Xg,
                                               int t0, size_t tstride) {
    const int qt = blockIdx.x;          // 0..25
    const int bct = blockIdx.y;         // 0..15
    const int t = t0 + blockIdx.z;
    ushort_t* Xgt = Xg + (size_t)blockIdx.z * tstride;
    const int tid = threadIdx.x;
    __shared__ ushort_t Ls[64][264];
    for (int idx = tid; idx < 4096; idx += 256) {
        int qr = idx >> 6, u = idx & 63;
        int q = qt * 64 + qr;
        us4 z;
        if (q < 1600) {
            int bc = bct * 256 + u * 4;
            int b = bc >> 6, c = bc & 63;
            const float4 v = *(const float4*)&sx[((((size_t)b * TT + t) * TK + (q & 3)) * TN + (q >> 2)) * TD + c];
            z[0] = f2bf(v.x); z[1] = f2bf(v.y); z[2] = f2bf(v.z); z[3] = f2bf(v.w);
        } else { z[0] = 0; z[1] = 0; z[2] = 0; z[3] = 0; }
        *(us4*)&Ls[qr][u * 4] = z;
    }
    __syncthreads();
    const int g = tid >> 3, seg = tid & 7;
    for (int p = 0; p < 8; ++p) {
        int bcl = p * 32 + g;
        us8 wv;
#pragma unroll
        for (int s = 0; s < 8; ++s) wv[s] = Ls[seg * 8 + s][bcl];
        *(us8*)&Xgt[(size_t)(bct * 256 + bcl) * QP + qt * 64 + seg * 8] = wv;
    }
}

// ---------------------------------------------------------------- xg1[p][bc] bf16 = supports @ X + rank-term (MFMA)
__global__ __launch_bounds__(256) void k_xg1(const ushort_t* __restrict__ Xg, const ushort_t* __restrict__ supN,
                                             const float* __restrict__ diag, const float* __restrict__ rv,
                                             ushort_t* __restrict__ xg1, int t0, size_t xgstride, size_t x1stride) {
    const int ntile = blockIdx.x;       // 0..4 (80 rows each)
    const int bct = blockIdx.y;         // 0..15 (256 cols each)
    const int zi = blockIdx.z;
    const int i = zi & 3, tz = zi >> 2;
    const int t = t0 + tz;
    const ushort_t* Xgt = Xg + (size_t)tz * xgstride;
    ushort_t* x1t = xg1 + (size_t)tz * x1stride;
    const int tid = threadIdx.x;
    const int w = tid >> 6, l = tid & 63;
    const int lr = l & 15, lk = (l >> 4) * 8;
    const int n0 = ntile * 80, bc0 = bct * 256;
    __shared__ ushort_t As[80][40];
    __shared__ ushort_t Xs[256][40];
    float4v acc[5][4] = {};
    const ushort_t* supt = supN + (size_t)t * TN * MP;
    for (int mc = 0; mc < 13; ++mc) {
        const int m0 = mc * 32;
        for (int idx = tid; idx < 640; idx += 256) {
            int r = idx >> 3, s = idx & 7;
            *(us4*)&As[r][s * 4] = *(const us4*)&supt[(size_t)(n0 + r) * MP + m0 + s * 4];
        }
        for (int idx = tid; idx < 1024; idx += 256) {
            int r = idx >> 2, s = idx & 3;
            *(us8*)&Xs[r][s * 8] = *(const us8*)&Xgt[(size_t)(bc0 + r) * QP + i * 400 + m0 + s * 8];
        }
        __syncthreads();
        short8v a[5], bfr[4];
#pragma unroll
        for (int fr = 0; fr < 5; ++fr) a[fr] = *(const short8v*)&As[fr * 16 + lr][lk];
#pragma unroll
        for (int ct = 0; ct < 4; ++ct) bfr[ct] = *(const short8v*)&Xs[w * 64 + ct * 16 + lr][lk];
#pragma unroll
        for (int fr = 0; fr < 5; ++fr)
#pragma unroll
            for (int ct = 0; ct < 4; ++ct)
                acc[fr][ct] = __builtin_amdgcn_mfma_f32_16x16x32_bf16(a[fr], bfr[ct], acc[fr][ct], 0, 0, 0);
        __syncthreads();
    }
    const float4 rv4 = *(const float4*)&rv[t * TK];
    const float rvj[4] = {rv4.x, rv4.y, rv4.z, rv4.w};
#pragma unroll
    for (int fr = 0; fr < 5; ++fr) {
        const int nb = n0 + fr * 16 + ((l >> 4) << 2);
        const float4 dg4 = *(const float4*)&diag[t * TN + nb];
        const float dg[4] = {dg4.x, dg4.y, dg4.z, dg4.w};
#pragma unroll
        for (int ct = 0; ct < 4; ++ct) {
            const int bc = bc0 + w * 64 + ct * 16 + lr;
            float rs[4] = {0.f, 0.f, 0.f, 0.f};
            for (int j = i; j < 4; ++j) {
                us4 xv = *(const us4*)&Xgt[(size_t)bc * QP + j * 400 + nb];
#pragma unroll
                for (int r = 0; r < 4; ++r) rs[r] += rvj[j] * bf2f(xv[r]);
            }
#pragma unroll
            for (int r = 0; r < 4; ++r) {
                float val = acc[fr][ct][r] + dg[r] * rs[r];
                x1t[(size_t)(i * TN + nb + r) * 4096 + bc] = f2bf(val);
            }
        }
    }
}

// ---------------------------------------------------------------- head v12: R5 math, i-split LDS (34.8KB, 4 blocks/CU),
// VGPR capped at 128 via launch_bounds(256,2); ih loop NOT unrolled (R11's spill lesson).
__global__ __launch_bounds__(256, 2) void k_head10(const float* __restrict__ sx, const ushort_t* __restrict__ xg1,
                                                   const float* __restrict__ Mn, const float* __restrict__ Mt,
                                                   const float* __restrict__ bn, const float* __restrict__ bt,
                                                   const int* __restrict__ idxs,
                                                   const float* __restrict__ gg, const float* __restrict__ gb,
                                                   const float* __restrict__ og, const float* __restrict__ ob,
                                                   float* __restrict__ out, int t0, size_t x1stride) {
    const int n = blockIdx.x;
    const int tz = blockIdx.y;
    const int t = t0 + tz;
    const ushort_t* x1t = xg1 + (size_t)tz * x1stride;
    const int tid = threadIdx.x;
    const int tx = tid & 15, ty = tid >> 4;
    const int o0 = tx * 4, b0 = ty * 4;
    __shared__ __align__(16) float Ml[64][68];
    __shared__ __align__(16) float Zl[64][68];
    float accout[4][4] = {};
    float g4[4], gb4[4];
#pragma unroll
    for (int c = 0; c < 4; c++) { g4[c] = gg[o0 + c]; gb4[c] = gb[o0 + c]; }
    const float* mnp = Mn + (size_t)n * 8192;

    for (int k = 0; k < TK; k++) {
        int tau = idxs[t * TK + k];
        const float* mtp = Mt + (size_t)tau * 8192;
        float acch[4][4] = {};
#pragma unroll 1
        for (int ih = 0; ih < 2; ih++) {
            // stage Ml half: i = ih*64 + il
            for (int idx = tid; idx < 1024; idx += 256) {
                int il = idx >> 4, o4 = idx & 15;
                const float4 a = *(const float4*)&mnp[(ih * 64 + il) * 64 + o4 * 4];
                const float4 c = *(const float4*)&mtp[(ih * 64 + il) * 64 + o4 * 4];
                float4 r; r.x = a.x + c.x; r.y = a.y + c.y; r.z = a.z + c.z; r.w = a.w + c.w;
                *(float4*)&Ml[il][o4 * 4] = r;
            }
            // stage Zl half
            if (ih == 0) {
                for (int idx = tid; idx < 1024; idx += 256) {
                    int b = idx >> 4, c4 = idx & 15;
                    const float4 v = *(const float4*)&sx[((((size_t)b * TT + t) * TK + k) * TN + n) * TD + c4 * 4];
                    *(float4*)&Zl[b][c4 * 4] = v;
                }
            } else {
                for (int idx = tid; idx < 512; idx += 256) {
                    int b = idx >> 3, s = idx & 7;
                    us8 xv = *(const us8*)&x1t[((size_t)n * TK + k) * 4096 + b * 64 + s * 8];
                    float* zp = &Zl[b][s * 8];
#pragma unroll
                    for (int q = 0; q < 8; q++) zp[q] = bf2f(xv[q]);
                }
            }
            __syncthreads();
            for (int i0 = 0; i0 < 64; i0 += 4) {
                float m[4][4];
#pragma unroll
                for (int q = 0; q < 4; q++) {
                    float4 mv = *(const float4*)&Ml[i0 + q][o0];
                    m[q][0] = mv.x; m[q][1] = mv.y; m[q][2] = mv.z; m[q][3] = mv.w;
                }
#pragma unroll
                for (int r = 0; r < 4; r++) {
                    float4 zv = *(const float4*)&Zl[b0 + r][i0];
                    float z[4] = {zv.x, zv.y, zv.z, zv.w};
#pragma unroll
                    for (int q = 0; q < 4; q++)
#pragma unroll
                        for (int c = 0; c < 4; c++) acch[r][c] += z[q] * m[q][c];
                }
            }
            __syncthreads();
        }
#pragma unroll
        for (int c = 0; c < 4; c++) {
            float bias = bn[n * TD + o0 + c] + bt[tau * TD + o0 + c];
#pragma unroll
            for (int r = 0; r < 4; r++) acch[r][c] += bias;
        }
#pragma unroll
        for (int r = 0; r < 4; r++) {
            float s1 = acch[r][0] + acch[r][1] + acch[r][2] + acch[r][3];
            float s2 = acch[r][0] * acch[r][0] + acch[r][1] * acch[r][1] +
                       acch[r][2] * acch[r][2] + acch[r][3] * acch[r][3];
#pragma unroll
            for (int mk = 1; mk < 16; mk <<= 1) { s1 += __shfl_xor(s1, mk); s2 += __shfl_xor(s2, mk); }
            float mean = s1 * (1.f / TD);
            float var  = s2 * (1.f / TD) - mean * mean;
            float rstd = rsqrtf(var + 1e-5f);
#pragma unroll
            for (int c = 0; c < 4; c++) accout[r][c] += (acch[r][c] - mean) * rstd * g4[c] + gb4[c];
        }
    }

    // ---- R5-verbatim epilogue ----
    float og4[4], ob4[4];
#pragma unroll
    for (int c = 0; c < 4; c++) { og4[c] = og[o0 + c]; ob4[c] = ob[o0 + c]; }
#pragma unroll
    for (int r = 0; r < 4; r++) {
        float pre[4];
#pragma unroll
        for (int c = 0; c < 4; c++) pre[c] = accout[r][c] * 0.25f;
        float s1 = pre[0] + pre[1] + pre[2] + pre[3];
        float s2 = pre[0] * pre[0] + pre[1] * pre[1] + pre[2] * pre[2] + pre[3] * pre[3];
#pragma unroll
        for (int mk2 = 1; mk2 < 16; mk2 <<= 1) { s1 += __shfl_xor(s1, mk2); s2 += __shfl_xor(s2, mk2); }
        float mean = s1 * (1.f / TD);
        float var  = s2 * (1.f / TD) - mean * mean;
        float rstd = rsqrtf(var + 1e-5f);
        float mk[4] = {0, 0, 0, 0};
        const float* sxp = &sx[(((size_t)(b0 + r) * TT + t) * TK) * TN * TD + (size_t)n * TD + o0];
#pragma unroll
        for (int k = 0; k < TK; k++) {
            float4 sv = *(const float4*)&sxp[(size_t)k * TN * TD];
            mk[0] += sv.x; mk[1] += sv.y; mk[2] += sv.z; mk[3] += sv.w;
        }
        float4 res;
        res.x = (pre[0] - mean) * rstd * og4[0] + ob4[0] + 0.25f * mk[0];
        res.y = (pre[1] - mean) * rstd * og4[1] + ob4[1] + 0.25f * mk[1];
        res.z = (pre[2] - mean) * rstd * og4[2] + ob4[2] + 0.25f * mk[2];
        res.w = (pre[3] - mean) * rstd * og4[3] + ob4[3] + 0.25f * mk[3];
        *reinterpret_cast<float4*>(&out[(((size_t)(b0 + r) * TT + t) * TN + n) * TD + o0]) = res;
    }
}

extern "C" void kernel_launch(void* const* d_in, const int* in_sizes, int n_in,
                              void* d_out, int out_size, void* d_ws, size_t ws_size,
                              hipStream_t stream) {
    (void)in_sizes; (void)n_in; (void)out_size;
    const float* sx    = (const float*)d_in[1];
    const float* rv    = (const float*)d_in[2];
    const int*   idxs  = (const int*)d_in[3];
    const float* node  = (const float*)d_in[4];
    const float* timee = (const float*)d_in[5];
    const float* leg   = (const float*)d_in[6];
    const float* leb   = (const float*)d_in[7];
    const float* wp    = (const float*)d_in[8];
    const float* bp    = (const float*)d_in[9];
    const float* gg    = (const float*)d_in[10];
    const float* gb    = (const float*)d_in[11];
    const float* og    = (const float*)d_in[12];
    const float* ob    = (const float*)d_in[13];
    float* out = (float*)d_out;

    char* w = (char*)d_ws;
    size_t off = 0;
    auto alloc = [&](size_t bytes) { size_t o = off; off = (off + bytes + 255) & ~(size_t)255; return o; };
    float*    embt = (float*)(w + alloc((size_t)TT * TN * TE * 4));
    ushort_t* supN = (ushort_t*)(w + alloc((size_t)TT * TN * MP * 2));
    float*    diag = (float*)(w + alloc((size_t)TT * TN * 4));
    float*    Mn   = (float*)(w + alloc((size_t)TN * 8192 * 4));
    float*    Mt   = (float*)(w + alloc((size_t)TT * 8192 * 4));
    float*    bn   = (float*)(w + alloc((size_t)TN * TD * 4));
    float*    bt   = (float*)(w + alloc((size_t)TT * TD * 4));
    const size_t xg_elems = (size_t)4096 * QP;     // per-t Xg (ushort)
    const size_t x1_elems = (size_t)1600 * 4096;   // per-t xg1 (ushort)
    const size_t small_end = off;
    const bool full = ws_size >= small_end + 12 * (xg_elems + x1_elems) * 2 + 1024;
    const int nt = full ? TT : 1;
    ushort_t* Xg = (ushort_t*)(w + alloc((size_t)nt * xg_elems * 2));
    ushort_t* x1 = (ushort_t*)(w + alloc((size_t)nt * x1_elems * 2));

    k_embt<<<dim3((TT * TN + 255) / 256), 256, 0, stream>>>(node, timee, leg, leb, embt);
    k_supports<<<dim3(TT * TN), 128, 0, stream>>>(embt, supN, diag);
    k_mix<<<dim3(TN), 256, 0, stream>>>(node, wp, bp, Mn, bn);
    k_mix<<<dim3(TT), 256, 0, stream>>>(timee, wp, bp, Mt, bt);
    if (full) {
        k_prepX<<<dim3(26, 16, TT), 256, 0, stream>>>(sx, Xg, 0, xg_elems);
        k_xg1<<<dim3(5, 16, 4 * TT), 256, 0, stream>>>(Xg, supN, diag, rv, x1, 0, xg_elems, x1_elems);
        k_head10<<<dim3(TN, TT), 256, 0, stream>>>(sx, x1, Mn, Mt, bn, bt, idxs, gg, gb, og, ob, out, 0, x1_elems);
    } else {
        for (int t = 0; t < TT; ++t) {
            k_prepX<<<dim3(26, 16, 1), 256, 0, stream>>>(sx, Xg, t, 0);
            k_xg1<<<dim3(5, 16, 4), 256, 0, stream>>>(Xg, supN, diag, rv, x1, t, 0, 0);
            k_head10<<<dim3(TN, 1), 256, 0, stream>>>(sx, x1, Mn, Mt, bn, bt, idxs, gg, gb, og, ob, out, t, 0);
        }
    }
}

// Round 13
// 947.076 us; speedup vs baseline: 4.3602x; 1.0062x over previous
//
#include <hip/hip_runtime.h>
#include <hip/hip_bf16.h>

#define TB 64
#define TT 12
#define TK 4
#define TN 400
#define TD 64
#define TE 16
#define QP 1664      // padded sxr rows: 1600 -> 26*64
#define MP 416       // padded supports K: 400 -> 13*32

typedef unsigned short ushort_t;
typedef __attribute__((ext_vector_type(8))) short short8v;
typedef __attribute__((ext_vector_type(4))) float float4v;
typedef __attribute__((ext_vector_type(4))) unsigned short us4;
typedef __attribute__((ext_vector_type(8))) unsigned short us8;

__device__ __forceinline__ float bf2f(ushort_t u) {
    union { unsigned int i; float f; } v; v.i = ((unsigned int)u) << 16; return v.f;
}
__device__ __forceinline__ ushort_t f2bf(float f) {
    union { float f; unsigned int i; } v; v.f = f;
    unsigned int u = v.i;
    return (ushort_t)((u + 0x7fffu + ((u >> 16) & 1u)) >> 16);
}

// ---------------------------------------------------------------- embt (LN of node+time embeddings)
__global__ void k_embt(const float* __restrict__ node, const float* __restrict__ timee,
                       const float* __restrict__ g, const float* __restrict__ b,
                       float* __restrict__ embt) {
    int id = blockIdx.x * blockDim.x + threadIdx.x;
    if (id >= TT * TN) return;
    int t = id / TN, n = id % TN;
    float v[TE];
    float s = 0.f;
#pragma unroll
    for (int e = 0; e < TE; e++) { v[e] = node[n * TE + e] + timee[t * TE + e]; s += v[e]; }
    float mean = s * (1.f / TE);
    float s2 = 0.f;
#pragma unroll
    for (int e = 0; e < TE; e++) { float d = v[e] - mean; s2 += d * d; }
    float rstd = rsqrtf(s2 * (1.f / TE) + 1e-12f);
#pragma unroll
    for (int e = 0; e < TE; e++) embt[(size_t)id * TE + e] = (v[e] - mean) * rstd * g[e] + b[e];
}

// ---------------------------------------------------------------- supports row-softmax -> supN bf16 [t][n][MP] (+diag fp32)
__global__ __launch_bounds__(128) void k_supports(const float* __restrict__ embt,
                                                  ushort_t* __restrict__ supN,
                                                  float* __restrict__ diag) {
    int t = blockIdx.x / TN, n = blockIdx.x % TN;
    int tid = threadIdx.x;
    __shared__ float row[TE];
    __shared__ float red[128];
    if (tid < TE) row[tid] = embt[((size_t)t * TN + n) * TE + tid];
    __syncthreads();
    float l[4];
    float lmax = -1e30f;
#pragma unroll
    for (int it = 0; it < 4; it++) {
        int m = tid + it * 128;
        float d = -1e30f;
        if (m < TN) {
            d = 0.f;
            const float* er = &embt[((size_t)t * TN + m) * TE];
#pragma unroll
            for (int e = 0; e < TE; e++) d += row[e] * er[e];
        }
        l[it] = d;
        lmax = fmaxf(lmax, d);
    }
    red[tid] = lmax; __syncthreads();
    for (int s = 64; s > 0; s >>= 1) { if (tid < s) red[tid] = fmaxf(red[tid], red[tid + s]); __syncthreads(); }
    float mx = red[0]; __syncthreads();
    float lsum = 0.f;
#pragma unroll
    for (int it = 0; it < 4; it++) {
        int m = tid + it * 128;
        if (m < TN) { l[it] = expf(l[it] - mx); lsum += l[it]; }
    }
    red[tid] = lsum; __syncthreads();
    for (int s = 64; s > 0; s >>= 1) { if (tid < s) red[tid] += red[tid + s]; __syncthreads(); }
    float inv = 1.f / red[0];
    ushort_t* srow = supN + ((size_t)t * TN + n) * MP;
#pragma unroll
    for (int it = 0; it < 4; it++) {
        int m = tid + it * 128;
        if (m < TN) {
            float v = l[it] * inv;
            srow[m] = f2bf(v);
            if (m == n) diag[t * TN + n] = v;
        }
    }
    if (tid < MP - TN) srow[TN + tid] = 0;  // zero K-pad
}

// ---------------------------------------------------------------- fp32 M[n][idx] (R2-proven): idx = cheb*4096 + d_in*64 + o
__global__ __launch_bounds__(256) void k_mix(const float* __restrict__ emb, const float* __restrict__ wp,
                                             const float* __restrict__ bp, float* __restrict__ M,
                                             float* __restrict__ bias) {
    int n = blockIdx.x;
    __shared__ float ev[TE];
    if (threadIdx.x < TE) ev[threadIdx.x] = emb[n * TE + threadIdx.x];
    __syncthreads();
    for (int idx = threadIdx.x; idx < 128 * TD; idx += 256) {
        float s = 0.f;
#pragma unroll
        for (int e = 0; e < TE; e++) s += ev[e] * wp[(size_t)e * 8192 + idx];
        M[(size_t)n * 8192 + idx] = s;
    }
    if (threadIdx.x < TD) {
        float s = 0.f;
#pragma unroll
        for (int e = 0; e < TE; e++) s += ev[e] * bp[e * TD + threadIdx.x];
        bias[n * TD + threadIdx.x] = s;
    }
}

// ---------------------------------------------------------------- Xg[bc][q] bf16 transpose of sxr (zero-padded q>=1600)
__global__ __launch_bounds__(256) void k_prepX(const float* __restrict__ sx, ushort_t* __restrict__ Xg,
                                               int t0, size_t tstride) {
    const int qt = blockIdx.x;          // 0..25
    const int bct = blockIdx.y;         // 0..15
    const int t = t0 + blockIdx.z;
    ushort_t* Xgt = Xg + (size_t)blockIdx.z * tstride;
    const int tid = threadIdx.x;
    __shared__ ushort_t Ls[64][264];
    for (int idx = tid; idx < 4096; idx += 256) {
        int qr = idx >> 6, u = idx & 63;
        int q = qt * 64 + qr;
        us4 z;
        if (q < 1600) {
            int bc = bct * 256 + u * 4;
            int b = bc >> 6, c = bc & 63;
            const float4 v = *(const float4*)&sx[((((size_t)b * TT + t) * TK + (q & 3)) * TN + (q >> 2)) * TD + c];
            z[0] = f2bf(v.x); z[1] = f2bf(v.y); z[2] = f2bf(v.z); z[3] = f2bf(v.w);
        } else { z[0] = 0; z[1] = 0; z[2] = 0; z[3] = 0; }
        *(us4*)&Ls[qr][u * 4] = z;
    }
    __syncthreads();
    const int g = tid >> 3, seg = tid & 7;
    for (int p = 0; p < 8; ++p) {
        int bcl = p * 32 + g;
        us8 wv;
#pragma unroll
        for (int s = 0; s < 8; ++s) wv[s] = Ls[seg * 8 + s][bcl];
        *(us8*)&Xgt[(size_t)(bct * 256 + bcl) * QP + qt * 64 + seg * 8] = wv;
    }
}

// ---------------------------------------------------------------- xg1 merged: one block = 80 rows x 128 bc x ALL 4 i.
// GEMM via MFMA; rank-term via in-LDS diagonal extraction + suffix registers (i descending). No epilogue HBM reads.
__global__ __launch_bounds__(256) void k_xg1m(const ushort_t* __restrict__ Xg, const ushort_t* __restrict__ supN,
                                              const float* __restrict__ diag, const float* __restrict__ rv,
                                              ushort_t* __restrict__ xg1, int t0, size_t xgstride, size_t x1stride) {
    const int ntile = blockIdx.x;       // 0..4 (80 rows)
    const int bct = blockIdx.y;         // 0..31 (128 bc)
    const int tz = blockIdx.z;
    const int t = t0 + tz;
    const ushort_t* Xgt = Xg + (size_t)tz * xgstride;
    ushort_t* x1t = xg1 + (size_t)tz * x1stride;
    const int tid = threadIdx.x;
    const int w = tid >> 6, l = tid & 63;
    const int lr = l & 15, lk = (l >> 4) * 8;
    const int n0 = ntile * 80, bc0 = bct * 128;
    __shared__ ushort_t As[80][40];
    __shared__ ushort_t Xs[128][40];
    const ushort_t* supt = supN + (size_t)t * TN * MP;
    const float4 rv4 = *(const float4*)&rv[t * TK];
    const float rvj[4] = {rv4.x, rv4.y, rv4.z, rv4.w};
    float4v rs[5][2] = {};   // suffix accumulators, persist across i

#pragma unroll 1
    for (int i = 3; i >= 0; --i) {
        const float rvi = rvj[i];
        float4v acc[5][2] = {};
        for (int mc = 0; mc < 13; ++mc) {
            const int m0 = mc * 32;
            for (int idx = tid; idx < 640; idx += 256) {
                int r = idx >> 3, s = idx & 7;
                *(us4*)&As[r][s * 4] = *(const us4*)&supt[(size_t)(n0 + r) * MP + m0 + s * 4];
            }
            for (int idx = tid; idx < 512; idx += 256) {
                int r = idx >> 2, s = idx & 3;
                *(us8*)&Xs[r][s * 8] = *(const us8*)&Xgt[(size_t)(bc0 + r) * QP + i * 400 + m0 + s * 8];
            }
            __syncthreads();
            short8v a[5], bfr[2];
#pragma unroll
            for (int fr = 0; fr < 5; ++fr) a[fr] = *(const short8v*)&As[fr * 16 + lr][lk];
#pragma unroll
            for (int ct = 0; ct < 2; ++ct) bfr[ct] = *(const short8v*)&Xs[w * 32 + ct * 16 + lr][lk];
#pragma unroll
            for (int fr = 0; fr < 5; ++fr)
#pragma unroll
                for (int ct = 0; ct < 2; ++ct)
                    acc[fr][ct] = __builtin_amdgcn_mfma_f32_16x16x32_bf16(a[fr], bfr[ct], acc[fr][ct], 0, 0, 0);
            // rank-term diagonal extraction: rs += rv_i * X_i[bc][nb] for nb in this chunk
            if (m0 + 32 > n0 && m0 < n0 + 80) {
#pragma unroll
                for (int fr = 0; fr < 5; ++fr)
#pragma unroll
                    for (int r = 0; r < 4; ++r) {
                        const int nb = n0 + fr * 16 + ((l >> 4) << 2) + r;
                        const int d = nb - m0;
                        if ((unsigned)d < 32u) {
#pragma unroll
                            for (int ct = 0; ct < 2; ++ct)
                                rs[fr][ct][r] += rvi * bf2f(Xs[w * 32 + ct * 16 + lr][d]);
                        }
                    }
            }
            __syncthreads();
        }
        // write rows for this i: val = acc + diag[nb]*rs
#pragma unroll
        for (int fr = 0; fr < 5; ++fr) {
            const int nb = n0 + fr * 16 + ((l >> 4) << 2);
            const float4 dg4 = *(const float4*)&diag[t * TN + nb];
            const float dg[4] = {dg4.x, dg4.y, dg4.z, dg4.w};
#pragma unroll
            for (int ct = 0; ct < 2; ++ct) {
                const int bc = bc0 + w * 32 + ct * 16 + lr;
#pragma unroll
                for (int r = 0; r < 4; ++r) {
                    float val = acc[fr][ct][r] + dg[r] * rs[fr][ct][r];
                    x1t[(size_t)(i * TN + nb + r) * 4096 + bc] = f2bf(val);
                }
            }
        }
    }
}

// ---------------------------------------------------------------- head v12 (R12-proven): R5 math, i-split LDS, (256,2)
__global__ __launch_bounds__(256, 2) void k_head10(const float* __restrict__ sx, const ushort_t* __restrict__ xg1,
                                                   const float* __restrict__ Mn, const float* __restrict__ Mt,
                                                   const float* __restrict__ bn, const float* __restrict__ bt,
                                                   const int* __restrict__ idxs,
                                                   const float* __restrict__ gg, const float* __restrict__ gb,
                                                   const float* __restrict__ og, const float* __restrict__ ob,
                                                   float* __restrict__ out, int t0, size_t x1stride) {
    const int n = blockIdx.x;
    const int tz = blockIdx.y;
    const int t = t0 + tz;
    const ushort_t* x1t = xg1 + (size_t)tz * x1stride;
    const int tid = threadIdx.x;
    const int tx = tid & 15, ty = tid >> 4;
    const int o0 = tx * 4, b0 = ty * 4;
    __shared__ __align__(16) float Ml[64][68];
    __shared__ __align__(16) float Zl[64][68];
    float accout[4][4] = {};
    float g4[4], gb4[4];
#pragma unroll
    for (int c = 0; c < 4; c++) { g4[c] = gg[o0 + c]; gb4[c] = gb[o0 + c]; }
    const float* mnp = Mn + (size_t)n * 8192;

    for (int k = 0; k < TK; k++) {
        int tau = idxs[t * TK + k];
        const float* mtp = Mt + (size_t)tau * 8192;
        float acch[4][4] = {};
#pragma unroll 1
        for (int ih = 0; ih < 2; ih++) {
            for (int idx = tid; idx < 1024; idx += 256) {
                int il = idx >> 4, o4 = idx & 15;
                const float4 a = *(const float4*)&mnp[(ih * 64 + il) * 64 + o4 * 4];
                const float4 c = *(const float4*)&mtp[(ih * 64 + il) * 64 + o4 * 4];
                float4 r; r.x = a.x + c.x; r.y = a.y + c.y; r.z = a.z + c.z; r.w = a.w + c.w;
                *(float4*)&Ml[il][o4 * 4] = r;
            }
            if (ih == 0) {
                for (int idx = tid; idx < 1024; idx += 256) {
                    int b = idx >> 4, c4 = idx & 15;
                    const float4 v = *(const float4*)&sx[((((size_t)b * TT + t) * TK + k) * TN + n) * TD + c4 * 4];
                    *(float4*)&Zl[b][c4 * 4] = v;
                }
            } else {
                for (int idx = tid; idx < 512; idx += 256) {
                    int b = idx >> 3, s = idx & 7;
                    us8 xv = *(const us8*)&x1t[((size_t)n * TK + k) * 4096 + b * 64 + s * 8];
                    float* zp = &Zl[b][s * 8];
#pragma unroll
                    for (int q = 0; q < 8; q++) zp[q] = bf2f(xv[q]);
                }
            }
            __syncthreads();
            for (int i0 = 0; i0 < 64; i0 += 4) {
                float m[4][4];
#pragma unroll
                for (int q = 0; q < 4; q++) {
                    float4 mv = *(const float4*)&Ml[i0 + q][o0];
                    m[q][0] = mv.x; m[q][1] = mv.y; m[q][2] = mv.z; m[q][3] = mv.w;
                }
#pragma unroll
                for (int r = 0; r < 4; r++) {
                    float4 zv = *(const float4*)&Zl[b0 + r][i0];
                    float z[4] = {zv.x, zv.y, zv.z, zv.w};
#pragma unroll
                    for (int q = 0; q < 4; q++)
#pragma unroll
                        for (int c = 0; c < 4; c++) acch[r][c] += z[q] * m[q][c];
                }
            }
            __syncthreads();
        }
#pragma unroll
        for (int c = 0; c < 4; c++) {
            float bias = bn[n * TD + o0 + c] + bt[tau * TD + o0 + c];
#pragma unroll
            for (int r = 0; r < 4; r++) acch[r][c] += bias;
        }
#pragma unroll
        for (int r = 0; r < 4; r++) {
            float s1 = acch[r][0] + acch[r][1] + acch[r][2] + acch[r][3];
            float s2 = acch[r][0] * acch[r][0] + acch[r][1] * acch[r][1] +
                       acch[r][2] * acch[r][2] + acch[r][3] * acch[r][3];
#pragma unroll
            for (int mk = 1; mk < 16; mk <<= 1) { s1 += __shfl_xor(s1, mk); s2 += __shfl_xor(s2, mk); }
            float mean = s1 * (1.f / TD);
            float var  = s2 * (1.f / TD) - mean * mean;
            float rstd = rsqrtf(var + 1e-5f);
#pragma unroll
            for (int c = 0; c < 4; c++) accout[r][c] += (acch[r][c] - mean) * rstd * g4[c] + gb4[c];
        }
    }

    float og4[4], ob4[4];
#pragma unroll
    for (int c = 0; c < 4; c++) { og4[c] = og[o0 + c]; ob4[c] = ob[o0 + c]; }
#pragma unroll
    for (int r = 0; r < 4; r++) {
        float pre[4];
#pragma unroll
        for (int c = 0; c < 4; c++) pre[c] = accout[r][c] * 0.25f;
        float s1 = pre[0] + pre[1] + pre[2] + pre[3];
        float s2 = pre[0] * pre[0] + pre[1] * pre[1] + pre[2] * pre[2] + pre[3] * pre[3];
#pragma unroll
        for (int mk2 = 1; mk2 < 16; mk2 <<= 1) { s1 += __shfl_xor(s1, mk2); s2 += __shfl_xor(s2, mk2); }
        float mean = s1 * (1.f / TD);
        float var  = s2 * (1.f / TD) - mean * mean;
        float rstd = rsqrtf(var + 1e-5f);
        float mk[4] = {0, 0, 0, 0};
        const float* sxp = &sx[(((size_t)(b0 + r) * TT + t) * TK) * TN * TD + (size_t)n * TD + o0];
#pragma unroll
        for (int k = 0; k < TK; k++) {
            float4 sv = *(const float4*)&sxp[(size_t)k * TN * TD];
            mk[0] += sv.x; mk[1] += sv.y; mk[2] += sv.z; mk[3] += sv.w;
        }
        float4 res;
        res.x = (pre[0] - mean) * rstd * og4[0] + ob4[0] + 0.25f * mk[0];
        res.y = (pre[1] - mean) * rstd * og4[1] + ob4[1] + 0.25f * mk[1];
        res.z = (pre[2] - mean) * rstd * og4[2] + ob4[2] + 0.25f * mk[2];
        res.w = (pre[3] - mean) * rstd * og4[3] + ob4[3] + 0.25f * mk[3];
        *reinterpret_cast<float4*>(&out[(((size_t)(b0 + r) * TT + t) * TN + n) * TD + o0]) = res;
    }
}

extern "C" void kernel_launch(void* const* d_in, const int* in_sizes, int n_in,
                              void* d_out, int out_size, void* d_ws, size_t ws_size,
                              hipStream_t stream) {
    (void)in_sizes; (void)n_in; (void)out_size;
    const float* sx    = (const float*)d_in[1];
    const float* rv    = (const float*)d_in[2];
    const int*   idxs  = (const int*)d_in[3];
    const float* node  = (const float*)d_in[4];
    const float* timee = (const float*)d_in[5];
    const float* leg   = (const float*)d_in[6];
    const float* leb   = (const float*)d_in[7];
    const float* wp    = (const float*)d_in[8];
    const float* bp    = (const float*)d_in[9];
    const float* gg    = (const float*)d_in[10];
    const float* gb    = (const float*)d_in[11];
    const float* og    = (const float*)d_in[12];
    const float* ob    = (const float*)d_in[13];
    float* out = (float*)d_out;

    char* w = (char*)d_ws;
    size_t off = 0;
    auto alloc = [&](size_t bytes) { size_t o = off; off = (off + bytes + 255) & ~(size_t)255; return o; };
    float*    embt = (float*)(w + alloc((size_t)TT * TN * TE * 4));
    ushort_t* supN = (ushort_t*)(w + alloc((size_t)TT * TN * MP * 2));
    float*    diag = (float*)(w + alloc((size_t)TT * TN * 4));
    float*    Mn   = (float*)(w + alloc((size_t)TN * 8192 * 4));
    float*    Mt   = (float*)(w + alloc((size_t)TT * 8192 * 4));
    float*    bn   = (float*)(w + alloc((size_t)TN * TD * 4));
    float*    bt   = (float*)(w + alloc((size_t)TT * TD * 4));
    const size_t xg_elems = (size_t)4096 * QP;     // per-t Xg (ushort)
    const size_t x1_elems = (size_t)1600 * 4096;   // per-t xg1 (ushort)
    const size_t small_end = off;
    const bool full = ws_size >= small_end + 12 * (xg_elems + x1_elems) * 2 + 1024;
    const int nt = full ? TT : 1;
    ushort_t* Xg = (ushort_t*)(w + alloc((size_t)nt * xg_elems * 2));
    ushort_t* x1 = (ushort_t*)(w + alloc((size_t)nt * x1_elems * 2));

    k_embt<<<dim3((TT * TN + 255) / 256), 256, 0, stream>>>(node, timee, leg, leb, embt);
    k_supports<<<dim3(TT * TN), 128, 0, stream>>>(embt, supN, diag);
    k_mix<<<dim3(TN), 256, 0, stream>>>(node, wp, bp, Mn, bn);
    k_mix<<<dim3(TT), 256, 0, stream>>>(timee, wp, bp, Mt, bt);
    if (full) {
        k_prepX<<<dim3(26, 16, TT), 256, 0, stream>>>(sx, Xg, 0, xg_elems);
        k_xg1m<<<dim3(5, 32, TT), 256, 0, stream>>>(Xg, supN, diag, rv, x1, 0, xg_elems, x1_elems);
        k_head10<<<dim3(TN, TT), 256, 0, stream>>>(sx, x1, Mn, Mt, bn, bt, idxs, gg, gb, og, ob, out, 0, x1_elems);
    } else {
        for (int t = 0; t < TT; ++t) {
            k_prepX<<<dim3(26, 16, 1), 256, 0, stream>>>(sx, Xg, t, 0);
            k_xg1m<<<dim3(5, 32, 1), 256, 0, stream>>>(Xg, supN, diag, rv, x1, t, 0, 0);
            k_head10<<<dim3(TN, 1), 256, 0, stream>>>(sx, x1, Mn, Mt, bn, bt, idxs, gg, gb, og, ob, out, t, 0);
        }
    }
}

// Round 14
// 726.333 us; speedup vs baseline: 5.6853x; 1.3039x over previous
//
#include <hip/hip_runtime.h>
#include <hip/hip_bf16.h>

#define TB 64
#define TT 12
#define TK 4
#define TN 400
#define TD 64
#define TE 16
#define QP 1664      // padded sxr rows: 1600 -> 26*64
#define MP 416       // padded supports K: 400 -> 13*32

typedef unsigned short ushort_t;
typedef __attribute__((ext_vector_type(8))) short short8v;
typedef __attribute__((ext_vector_type(4))) float float4v;
typedef __attribute__((ext_vector_type(4))) unsigned short us4;
typedef __attribute__((ext_vector_type(8))) unsigned short us8;

__device__ __forceinline__ float bf2f(ushort_t u) {
    union { unsigned int i; float f; } v; v.i = ((unsigned int)u) << 16; return v.f;
}
__device__ __forceinline__ ushort_t f2bf(float f) {
    union { float f; unsigned int i; } v; v.f = f;
    unsigned int u = v.i;
    return (ushort_t)((u + 0x7fffu + ((u >> 16) & 1u)) >> 16);
}

// ---------------------------------------------------------------- embt (LN of node+time embeddings)
__global__ void k_embt(const float* __restrict__ node, const float* __restrict__ timee,
                       const float* __restrict__ g, const float* __restrict__ b,
                       float* __restrict__ embt) {
    int id = blockIdx.x * blockDim.x + threadIdx.x;
    if (id >= TT * TN) return;
    int t = id / TN, n = id % TN;
    float v[TE];
    float s = 0.f;
#pragma unroll
    for (int e = 0; e < TE; e++) { v[e] = node[n * TE + e] + timee[t * TE + e]; s += v[e]; }
    float mean = s * (1.f / TE);
    float s2 = 0.f;
#pragma unroll
    for (int e = 0; e < TE; e++) { float d = v[e] - mean; s2 += d * d; }
    float rstd = rsqrtf(s2 * (1.f / TE) + 1e-12f);
#pragma unroll
    for (int e = 0; e < TE; e++) embt[(size_t)id * TE + e] = (v[e] - mean) * rstd * g[e] + b[e];
}

// ---------------------------------------------------------------- supports row-softmax -> supN bf16 [t][n][MP] (+diag fp32)
__global__ __launch_bounds__(128) void k_supports(const float* __restrict__ embt,
                                                  ushort_t* __restrict__ supN,
                                                  float* __restrict__ diag) {
    int t = blockIdx.x / TN, n = blockIdx.x % TN;
    int tid = threadIdx.x;
    __shared__ float row[TE];
    __shared__ float red[128];
    if (tid < TE) row[tid] = embt[((size_t)t * TN + n) * TE + tid];
    __syncthreads();
    float l[4];
    float lmax = -1e30f;
#pragma unroll
    for (int it = 0; it < 4; it++) {
        int m = tid + it * 128;
        float d = -1e30f;
        if (m < TN) {
            d = 0.f;
            const float* er = &embt[((size_t)t * TN + m) * TE];
#pragma unroll
            for (int e = 0; e < TE; e++) d += row[e] * er[e];
        }
        l[it] = d;
        lmax = fmaxf(lmax, d);
    }
    red[tid] = lmax; __syncthreads();
    for (int s = 64; s > 0; s >>= 1) { if (tid < s) red[tid] = fmaxf(red[tid], red[tid + s]); __syncthreads(); }
    float mx = red[0]; __syncthreads();
    float lsum = 0.f;
#pragma unroll
    for (int it = 0; it < 4; it++) {
        int m = tid + it * 128;
        if (m < TN) { l[it] = expf(l[it] - mx); lsum += l[it]; }
    }
    red[tid] = lsum; __syncthreads();
    for (int s = 64; s > 0; s >>= 1) { if (tid < s) red[tid] += red[tid + s]; __syncthreads(); }
    float inv = 1.f / red[0];
    ushort_t* srow = supN + ((size_t)t * TN + n) * MP;
#pragma unroll
    for (int it = 0; it < 4; it++) {
        int m = tid + it * 128;
        if (m < TN) {
            float v = l[it] * inv;
            srow[m] = f2bf(v);
            if (m == n) diag[t * TN + n] = v;
        }
    }
    if (tid < MP - TN) srow[TN + tid] = 0;  // zero K-pad
}

// ---------------------------------------------------------------- fp32 M[n][idx] (R2-proven): idx = cheb*4096 + d_in*64 + o
__global__ __launch_bounds__(256) void k_mix(const float* __restrict__ emb, const float* __restrict__ wp,
                                             const float* __restrict__ bp, float* __restrict__ M,
                                             float* __restrict__ bias) {
    int n = blockIdx.x;
    __shared__ float ev[TE];
    if (threadIdx.x < TE) ev[threadIdx.x] = emb[n * TE + threadIdx.x];
    __syncthreads();
    for (int idx = threadIdx.x; idx < 128 * TD; idx += 256) {
        float s = 0.f;
#pragma unroll
        for (int e = 0; e < TE; e++) s += ev[e] * wp[(size_t)e * 8192 + idx];
        M[(size_t)n * 8192 + idx] = s;
    }
    if (threadIdx.x < TD) {
        float s = 0.f;
#pragma unroll
        for (int e = 0; e < TE; e++) s += ev[e] * bp[e * TD + threadIdx.x];
        bias[n * TD + threadIdx.x] = s;
    }
}

// ---------------------------------------------------------------- Xg[bc][q] bf16 transpose of sxr (zero-padded q>=1600)
__global__ __launch_bounds__(256) void k_prepX(const float* __restrict__ sx, ushort_t* __restrict__ Xg,
                                               int t0, size_t tstride) {
    const int qt = blockIdx.x;          // 0..25
    const int bct = blockIdx.y;         // 0..15
    const int t = t0 + blockIdx.z;
    ushort_t* Xgt = Xg + (size_t)blockIdx.z * tstride;
    const int tid = threadIdx.x;
    __shared__ ushort_t Ls[64][264];
    for (int idx = tid; idx < 4096; idx += 256) {
        int qr = idx >> 6, u = idx & 63;
        int q = qt * 64 + qr;
        us4 z;
        if (q < 1600) {
            int bc = bct * 256 + u * 4;
            int b = bc >> 6, c = bc & 63;
            const float4 v = *(const float4*)&sx[((((size_t)b * TT + t) * TK + (q & 3)) * TN + (q >> 2)) * TD + c];
            z[0] = f2bf(v.x); z[1] = f2bf(v.y); z[2] = f2bf(v.z); z[3] = f2bf(v.w);
        } else { z[0] = 0; z[1] = 0; z[2] = 0; z[3] = 0; }
        *(us4*)&Ls[qr][u * 4] = z;
    }
    __syncthreads();
    const int g = tid >> 3, seg = tid & 7;
    for (int p = 0; p < 8; ++p) {
        int bcl = p * 32 + g;
        us8 wv;
#pragma unroll
        for (int s = 0; s < 8; ++s) wv[s] = Ls[seg * 8 + s][bcl];
        *(us8*)&Xgt[(size_t)(bct * 256 + bcl) * QP + qt * 64 + seg * 8] = wv;
    }
}

// ---------------------------------------------------------------- xg1 merged + double-buffered reg prefetch:
// one block = 80 rows x 128 bc x ALL 4 i; chunk c+1 loads issued before chunk c compute; 1 barrier/iter.
#define ISSUE(ii, mm0) do { \
    ra0 = *(const us4*)&supt[(size_t)(n0 + (tid >> 3)) * MP + (mm0) + (tid & 7) * 4]; \
    { int idx_ = tid + 256; ra1 = *(const us4*)&supt[(size_t)(n0 + (idx_ >> 3)) * MP + (mm0) + (idx_ & 7) * 4]; } \
    if (tid < 128) { int idx_ = tid + 512; ra2 = *(const us4*)&supt[(size_t)(n0 + (idx_ >> 3)) * MP + (mm0) + (idx_ & 7) * 4]; } \
    rx0 = *(const us8*)&Xgt[(size_t)(bc0 + (tid >> 2)) * QP + (ii) * 400 + (mm0) + (tid & 3) * 8]; \
    { int idx_ = tid + 256; rx1 = *(const us8*)&Xgt[(size_t)(bc0 + (idx_ >> 2)) * QP + (ii) * 400 + (mm0) + (idx_ & 3) * 8]; } \
} while (0)

#define COMMIT(buf) do { \
    *(us4*)&As[buf][tid >> 3][(tid & 7) * 4] = ra0; \
    { int idx_ = tid + 256; *(us4*)&As[buf][idx_ >> 3][(idx_ & 7) * 4] = ra1; } \
    if (tid < 128) { int idx_ = tid + 512; *(us4*)&As[buf][idx_ >> 3][(idx_ & 7) * 4] = ra2; } \
    *(us8*)&Xs[buf][tid >> 2][(tid & 3) * 8] = rx0; \
    { int idx_ = tid + 256; *(us8*)&Xs[buf][idx_ >> 2][(idx_ & 3) * 8] = rx1; } \
} while (0)

__global__ __launch_bounds__(256, 2) void k_xg1m(const ushort_t* __restrict__ Xg, const ushort_t* __restrict__ supN,
                                                 const float* __restrict__ diag, const float* __restrict__ rv,
                                                 ushort_t* __restrict__ xg1, int t0, size_t xgstride, size_t x1stride) {
    const int ntile = blockIdx.x;       // 0..4 (80 rows)
    const int bct = blockIdx.y;         // 0..31 (128 bc)
    const int tz = blockIdx.z;
    const int t = t0 + tz;
    const ushort_t* Xgt = Xg + (size_t)tz * xgstride;
    ushort_t* x1t = xg1 + (size_t)tz * x1stride;
    const int tid = threadIdx.x;
    const int w = tid >> 6, l = tid & 63;
    const int lr = l & 15, lk = (l >> 4) * 8;
    const int n0 = ntile * 80, bc0 = bct * 128;
    __shared__ ushort_t As[2][80][40];
    __shared__ ushort_t Xs[2][128][40];
    const ushort_t* supt = supN + (size_t)t * TN * MP;
    const float4 rv4 = *(const float4*)&rv[t * TK];
    const float rvj[4] = {rv4.x, rv4.y, rv4.z, rv4.w};
    float4v rs[5][2] = {};   // suffix accumulators, persist across i
    float4v acc[5][2] = {};
    us4 ra0, ra1, ra2;
    us8 rx0, rx1;

    ISSUE(3, 0);
    COMMIT(0);
    __syncthreads();
    int cur = 0;
#pragma unroll 1
    for (int c = 0; c < 52; ++c) {
        const int i = 3 - c / 13;
        const int m0 = (c % 13) * 32;
        if (c + 1 < 52) {
            const int i2 = 3 - (c + 1) / 13;
            const int m02 = ((c + 1) % 13) * 32;
            ISSUE(i2, m02);
        }
        // compute chunk c from buf[cur]
        short8v bfr[2];
#pragma unroll
        for (int ct = 0; ct < 2; ++ct) bfr[ct] = *(const short8v*)&Xs[cur][w * 32 + ct * 16 + lr][lk];
#pragma unroll
        for (int fr = 0; fr < 5; ++fr) {
            short8v a = *(const short8v*)&As[cur][fr * 16 + lr][lk];
#pragma unroll
            for (int ct = 0; ct < 2; ++ct)
                acc[fr][ct] = __builtin_amdgcn_mfma_f32_16x16x32_bf16(a, bfr[ct], acc[fr][ct], 0, 0, 0);
        }
        // rank-term diagonal extraction: rs += rv_i * X_i[bc][nb] for nb in this chunk
        if (m0 + 32 > n0 && m0 < n0 + 80) {
            const float rvi = rvj[i];
#pragma unroll
            for (int fr = 0; fr < 5; ++fr)
#pragma unroll
                for (int r = 0; r < 4; ++r) {
                    const int nb = n0 + fr * 16 + ((l >> 4) << 2) + r;
                    const int d = nb - m0;
                    if ((unsigned)d < 32u) {
#pragma unroll
                        for (int ct = 0; ct < 2; ++ct)
                            rs[fr][ct][r] += rvi * bf2f(Xs[cur][w * 32 + ct * 16 + lr][d]);
                    }
                }
        }
        // end of this i: write x1 rows (val = acc + diag*rs), reset acc
        if ((c % 13) == 12) {
#pragma unroll
            for (int fr = 0; fr < 5; ++fr) {
                const int nb = n0 + fr * 16 + ((l >> 4) << 2);
                const float4 dg4 = *(const float4*)&diag[t * TN + nb];
                const float dg[4] = {dg4.x, dg4.y, dg4.z, dg4.w};
#pragma unroll
                for (int ct = 0; ct < 2; ++ct) {
                    const int bc = bc0 + w * 32 + ct * 16 + lr;
#pragma unroll
                    for (int r = 0; r < 4; ++r) {
                        float val = acc[fr][ct][r] + dg[r] * rs[fr][ct][r];
                        x1t[(size_t)(i * TN + nb + r) * 4096 + bc] = f2bf(val);
                    }
                    acc[fr][ct] = (float4v){0.f, 0.f, 0.f, 0.f};
                }
            }
        }
        if (c + 1 < 52) COMMIT(cur ^ 1);
        __syncthreads();
        cur ^= 1;
    }
}

// ---------------------------------------------------------------- head v12 (R12-proven): R5 math, i-split LDS, (256,2)
__global__ __launch_bounds__(256, 2) void k_head10(const float* __restrict__ sx, const ushort_t* __restrict__ xg1,
                                                   const float* __restrict__ Mn, const float* __restrict__ Mt,
                                                   const float* __restrict__ bn, const float* __restrict__ bt,
                                                   const int* __restrict__ idxs,
                                                   const float* __restrict__ gg, const float* __restrict__ gb,
                                                   const float* __restrict__ og, const float* __restrict__ ob,
                                                   float* __restrict__ out, int t0, size_t x1stride) {
    const int n = blockIdx.x;
    const int tz = blockIdx.y;
    const int t = t0 + tz;
    const ushort_t* x1t = xg1 + (size_t)tz * x1stride;
    const int tid = threadIdx.x;
    const int tx = tid & 15, ty = tid >> 4;
    const int o0 = tx * 4, b0 = ty * 4;
    __shared__ __align__(16) float Ml[64][68];
    __shared__ __align__(16) float Zl[64][68];
    float accout[4][4] = {};
    float g4[4], gb4[4];
#pragma unroll
    for (int c = 0; c < 4; c++) { g4[c] = gg[o0 + c]; gb4[c] = gb[o0 + c]; }
    const float* mnp = Mn + (size_t)n * 8192;

    for (int k = 0; k < TK; k++) {
        int tau = idxs[t * TK + k];
        const float* mtp = Mt + (size_t)tau * 8192;
        float acch[4][4] = {};
#pragma unroll 1
        for (int ih = 0; ih < 2; ih++) {
            for (int idx = tid; idx < 1024; idx += 256) {
                int il = idx >> 4, o4 = idx & 15;
                const float4 a = *(const float4*)&mnp[(ih * 64 + il) * 64 + o4 * 4];
                const float4 c = *(const float4*)&mtp[(ih * 64 + il) * 64 + o4 * 4];
                float4 r; r.x = a.x + c.x; r.y = a.y + c.y; r.z = a.z + c.z; r.w = a.w + c.w;
                *(float4*)&Ml[il][o4 * 4] = r;
            }
            if (ih == 0) {
                for (int idx = tid; idx < 1024; idx += 256) {
                    int b = idx >> 4, c4 = idx & 15;
                    const float4 v = *(const float4*)&sx[((((size_t)b * TT + t) * TK + k) * TN + n) * TD + c4 * 4];
                    *(float4*)&Zl[b][c4 * 4] = v;
                }
            } else {
                for (int idx = tid; idx < 512; idx += 256) {
                    int b = idx >> 3, s = idx & 7;
                    us8 xv = *(const us8*)&x1t[((size_t)n * TK + k) * 4096 + b * 64 + s * 8];
                    float* zp = &Zl[b][s * 8];
#pragma unroll
                    for (int q = 0; q < 8; q++) zp[q] = bf2f(xv[q]);
                }
            }
            __syncthreads();
            for (int i0 = 0; i0 < 64; i0 += 4) {
                float m[4][4];
#pragma unroll
                for (int q = 0; q < 4; q++) {
                    float4 mv = *(const float4*)&Ml[i0 + q][o0];
                    m[q][0] = mv.x; m[q][1] = mv.y; m[q][2] = mv.z; m[q][3] = mv.w;
                }
#pragma unroll
                for (int r = 0; r < 4; r++) {
                    float4 zv = *(const float4*)&Zl[b0 + r][i0];
                    float z[4] = {zv.x, zv.y, zv.z, zv.w};
#pragma unroll
                    for (int q = 0; q < 4; q++)
#pragma unroll
                        for (int c = 0; c < 4; c++) acch[r][c] += z[q] * m[q][c];
                }
            }
            __syncthreads();
        }
#pragma unroll
        for (int c = 0; c < 4; c++) {
            float bias = bn[n * TD + o0 + c] + bt[tau * TD + o0 + c];
#pragma unroll
            for (int r = 0; r < 4; r++) acch[r][c] += bias;
        }
#pragma unroll
        for (int r = 0; r < 4; r++) {
            float s1 = acch[r][0] + acch[r][1] + acch[r][2] + acch[r][3];
            float s2 = acch[r][0] * acch[r][0] + acch[r][1] * acch[r][1] +
                       acch[r][2] * acch[r][2] + acch[r][3] * acch[r][3];
#pragma unroll
            for (int mk = 1; mk < 16; mk <<= 1) { s1 += __shfl_xor(s1, mk); s2 += __shfl_xor(s2, mk); }
            float mean = s1 * (1.f / TD);
            float var  = s2 * (1.f / TD) - mean * mean;
            float rstd = rsqrtf(var + 1e-5f);
#pragma unroll
            for (int c = 0; c < 4; c++) accout[r][c] += (acch[r][c] - mean) * rstd * g4[c] + gb4[c];
        }
    }

    float og4[4], ob4[4];
#pragma unroll
    for (int c = 0; c < 4; c++) { og4[c] = og[o0 + c]; ob4[c] = ob[o0 + c]; }
#pragma unroll
    for (int r = 0; r < 4; r++) {
        float pre[4];
#pragma unroll
        for (int c = 0; c < 4; c++) pre[c] = accout[r][c] * 0.25f;
        float s1 = pre[0] + pre[1] + pre[2] + pre[3];
        float s2 = pre[0] * pre[0] + pre[1] * pre[1] + pre[2] * pre[2] + pre[3] * pre[3];
#pragma unroll
        for (int mk2 = 1; mk2 < 16; mk2 <<= 1) { s1 += __shfl_xor(s1, mk2); s2 += __shfl_xor(s2, mk2); }
        float mean = s1 * (1.f / TD);
        float var  = s2 * (1.f / TD) - mean * mean;
        float rstd = rsqrtf(var + 1e-5f);
        float mk[4] = {0, 0, 0, 0};
        const float* sxp = &sx[(((size_t)(b0 + r) * TT + t) * TK) * TN * TD + (size_t)n * TD + o0];
#pragma unroll
        for (int k = 0; k < TK; k++) {
            float4 sv = *(const float4*)&sxp[(size_t)k * TN * TD];
            mk[0] += sv.x; mk[1] += sv.y; mk[2] += sv.z; mk[3] += sv.w;
        }
        float4 res;
        res.x = (pre[0] - mean) * rstd * og4[0] + ob4[0] + 0.25f * mk[0];
        res.y = (pre[1] - mean) * rstd * og4[1] + ob4[1] + 0.25f * mk[1];
        res.z = (pre[2] - mean) * rstd * og4[2] + ob4[2] + 0.25f * mk[2];
        res.w = (pre[3] - mean) * rstd * og4[3] + ob4[3] + 0.25f * mk[3];
        *reinterpret_cast<float4*>(&out[(((size_t)(b0 + r) * TT + t) * TN + n) * TD + o0]) = res;
    }
}

extern "C" void kernel_launch(void* const* d_in, const int* in_sizes, int n_in,
                              void* d_out, int out_size, void* d_ws, size_t ws_size,
                              hipStream_t stream) {
    (void)in_sizes; (void)n_in; (void)out_size;
    const float* sx    = (const float*)d_in[1];
    const float* rv    = (const float*)d_in[2];
    const int*   idxs  = (const int*)d_in[3];
    const float* node  = (const float*)d_in[4];
    const float* timee = (const float*)d_in[5];
    const float* leg   = (const float*)d_in[6];
    const float* leb   = (const float*)d_in[7];
    const float* wp    = (const float*)d_in[8];
    const float* bp    = (const float*)d_in[9];
    const float* gg    = (const float*)d_in[10];
    const float* gb    = (const float*)d_in[11];
    const float* og    = (const float*)d_in[12];
    const float* ob    = (const float*)d_in[13];
    float* out = (float*)d_out;

    char* w = (char*)d_ws;
    size_t off = 0;
    auto alloc = [&](size_t bytes) { size_t o = off; off = (off + bytes + 255) & ~(size_t)255; return o; };
    float*    embt = (float*)(w + alloc((size_t)TT * TN * TE * 4));
    ushort_t* supN = (ushort_t*)(w + alloc((size_t)TT * TN * MP * 2));
    float*    diag = (float*)(w + alloc((size_t)TT * TN * 4));
    float*    Mn   = (float*)(w + alloc((size_t)TN * 8192 * 4));
    float*    Mt   = (float*)(w + alloc((size_t)TT * 8192 * 4));
    float*    bn   = (float*)(w + alloc((size_t)TN * TD * 4));
    float*    bt   = (float*)(w + alloc((size_t)TT * TD * 4));
    const size_t xg_elems = (size_t)4096 * QP;     // per-t Xg (ushort)
    const size_t x1_elems = (size_t)1600 * 4096;   // per-t xg1 (ushort)
    const size_t small_end = off;
    const bool full = ws_size >= small_end + 12 * (xg_elems + x1_elems) * 2 + 1024;
    const int nt = full ? TT : 1;
    ushort_t* Xg = (ushort_t*)(w + alloc((size_t)nt * xg_elems * 2));
    ushort_t* x1 = (ushort_t*)(w + alloc((size_t)nt * x1_elems * 2));

    k_embt<<<dim3((TT * TN + 255) / 256), 256, 0, stream>>>(node, timee, leg, leb, embt);
    k_supports<<<dim3(TT * TN), 128, 0, stream>>>(embt, supN, diag);
    k_mix<<<dim3(TN), 256, 0, stream>>>(node, wp, bp, Mn, bn);
    k_mix<<<dim3(TT), 256, 0, stream>>>(timee, wp, bp, Mt, bt);
    if (full) {
        k_prepX<<<dim3(26, 16, TT), 256, 0, stream>>>(sx, Xg, 0, xg_elems);
        k_xg1m<<<dim3(5, 32, TT), 256, 0, stream>>>(Xg, supN, diag, rv, x1, 0, xg_elems, x1_elems);
        k_head10<<<dim3(TN, TT), 256, 0, stream>>>(sx, x1, Mn, Mt, bn, bt, idxs, gg, gb, og, ob, out, 0, x1_elems);
    } else {
        for (int t = 0; t < TT; ++t) {
            k_prepX<<<dim3(26, 16, 1), 256, 0, stream>>>(sx, Xg, t, 0);
            k_xg1m<<<dim3(5, 32, 1), 256, 0, stream>>>(Xg, supN, diag, rv, x1, t, 0, 0);
            k_head10<<<dim3(TN, 1), 256, 0, stream>>>(sx, x1, Mn, Mt, bn, bt, idxs, gg, gb, og, ob, out, t, 0);
        }
    }
}